// Round 11
// baseline (393.447 us; speedup 1.0000x reference)
//
#include <hip/hip_runtime.h>
#include <stdint.h>

// Shapes: B=16 T=8 C=2048 H=16 W=8 -> C8=256 C4=512 HW=128 NP=4
// NIMG = B*T = 128, M = NIMG*HW = 16384, Ncat = 2*C8 = 512, K = 2048

typedef _Float16 f16;
typedef _Float16 f16x4 __attribute__((ext_vector_type(4)));
typedef _Float16 f16x8 __attribute__((ext_vector_type(8)));
typedef float f32x4 __attribute__((ext_vector_type(4)));

typedef const void __attribute__((address_space(1)))* gptr1;
typedef void __attribute__((address_space(3)))* lptr3;

__device__ __forceinline__ void gload16(const void* g, void* l) {
  __builtin_amdgcn_global_load_lds((gptr1)g, (lptr3)l, 16, 0, 0);
}

__device__ __forceinline__ float sigmoidf_(float x) { return 1.f / (1.f + expf(-x)); }

#define WAIT_VM6 asm volatile("s_waitcnt vmcnt(6)" ::: "memory")
#define WAIT_VM0 asm volatile("s_waitcnt vmcnt(0)" ::: "memory")
#define WAIT_LGKM8 asm volatile("s_waitcnt lgkmcnt(8)" ::: "memory")
#define WAIT_LGKM0 asm volatile("s_waitcnt lgkmcnt(0)" ::: "memory")

// ---------------- Merged Prep + P1 (unchanged from round 10) ----------------
__global__ __launch_bounds__(256) void kPP(const float* __restrict__ x,
                                           f16* __restrict__ Af,
                                           const float* __restrict__ gw, const float* __restrict__ gs,
                                           const float* __restrict__ bw, const float* __restrict__ bs,
                                           const float* __restrict__ gg_w, const float* __restrict__ gg_s,
                                           const float* __restrict__ tte_w, const float* __restrict__ tte_s,
                                           const float* __restrict__ thw, const float* __restrict__ w1,
                                           const float* __restrict__ w2,
                                           f16* __restrict__ Wf,
                                           float* __restrict__ ggT, float* __restrict__ tteT,
                                           float* __restrict__ thwT, float* __restrict__ w1T,
                                           float* __restrict__ w2T) {
  __shared__ __align__(16) char shmem[64 * 65 * 4];
  int t = threadIdx.x;
  int bid = blockIdx.x;
  if (bid < 8192) {
    float (*L)[65] = (float(*)[65])shmem;
    int n = bid >> 6;
    int kc = (bid >> 1) & 31;
    int hh = bid & 1;
    int k0 = kc * 64;
    const float* src = x + (size_t)n * 262144 + (size_t)k0 * 128 + hh * 64;
    for (int r = 0; r < 4; ++r) {
      int f = r * 256 + t;
      int kk = f >> 4, c4 = (f & 15) * 4;
      float4 v = *(const float4*)(src + (size_t)kk * 128 + c4);
      L[kk][c4 + 0] = v.x; L[kk][c4 + 1] = v.y; L[kk][c4 + 2] = v.z; L[kk][c4 + 3] = v.w;
    }
    __syncthreads();
    for (int r = 0; r < 2; ++r) {
      int id = r * 256 + t;
      int hw = id >> 3, c = id & 7;
      int cs = c ^ (hw & 7);
      f16x8 h8;
      for (int j = 0; j < 8; ++j)
        h8[j] = (f16)L[cs * 8 + j][hw];
      size_t m = (size_t)n * 128 + hh * 64 + hw;
      size_t ob = m * 2048 + (size_t)k0 + (size_t)c * 8;
      *(f16x8*)(Af + ob) = h8;
    }
    return;
  }
  if (bid < 8704) {
    int id = (bid - 8192) * 256 + t;
    int o = id >> 8, cch = id & 255;
    float s; const float* row;
    if (o < 256) { s = gs[o]; row = gw + (size_t)o * 2048; }
    else         { s = bs[o - 256]; row = bw + (size_t)(o - 256) * 2048; }
    int kb = cch >> 3, sub = cch & 7;
    int subd = sub ^ (o & 7);
    f16x8 h8;
    for (int j = 0; j < 8; ++j)
      h8[j] = (f16)(row[cch * 8 + j] * s);
    size_t ob = (size_t)o * 2048 + (size_t)kb * 64 + (size_t)subd * 8;
    *(f16x8*)(Wf + ob) = h8;
    return;
  }
  float (*TL)[65] = (float(*)[65])shmem;
  int tb = bid - 8704;
  const float* src; float* dst; const float* scale = nullptr; int R, C;
  if (tb < 128)      { src = thw;   dst = thwT; R = 256;  C = 2048; }
  else if (tb < 256) { tb -= 128; src = w2;  dst = w2T;  R = 2048; C = 256; }
  else if (tb < 288) { tb -= 256; src = w1;  dst = w1T;  R = 256;  C = 512; }
  else if (tb < 296) { tb -= 288; src = gg_w;  dst = ggT;  scale = gg_s;  R = 128; C = 256; }
  else               { tb -= 296; src = tte_w; dst = tteT; scale = tte_s; R = 128; C = 256; }
  int tpc = C >> 6;
  int r0 = (tb / tpc) * 64, c0 = (tb % tpc) * 64;
  int i16 = t >> 4, j4 = (t & 15) * 4;
  for (int s = 0; s < 4; ++s) {
    int i = i16 + s * 16;
    float4 v = *(const float4*)(src + (size_t)(r0 + i) * C + c0 + j4);
    TL[i][j4 + 0] = v.x; TL[i][j4 + 1] = v.y; TL[i][j4 + 2] = v.z; TL[i][j4 + 3] = v.w;
  }
  __syncthreads();
  for (int s = 0; s < 4; ++s) {
    int j = i16 + s * 16;
    float4 w;
    w.x = TL[j4 + 0][j]; w.y = TL[j4 + 1][j]; w.z = TL[j4 + 2][j]; w.w = TL[j4 + 3][j];
    if (scale) {
      w.x *= scale[r0 + j4 + 0]; w.y *= scale[r0 + j4 + 1];
      w.z *= scale[r0 + j4 + 2]; w.w *= scale[r0 + j4 + 3];
    }
    *(float4*)(dst + (size_t)(c0 + j) * R + r0 + j4) = w;
  }
}

// ---------------- Stage A GEMM (unchanged round-7 schedule, f16 outputs) ----------------
__global__ __launch_bounds__(512, 2) void kGemm8(const f16* __restrict__ Af, const f16* __restrict__ Wf,
                                                 const float* __restrict__ gamma_b, const float* __restrict__ beta_b,
                                                 f16* __restrict__ gammaFh, f16* __restrict__ betaFh) {
  __shared__ __align__(16) f16 S[3][24576];
  int t = threadIdx.x;
  int lane = t & 63, wid = t >> 6;
  int wr = wid >> 2, wc = wid & 3;
  int bid = blockIdx.x;
  int bx = (bid & 7) * 16 + (bid >> 4);
  int by = (bid >> 3) & 1;
  size_t M0 = (size_t)bx * 128;
  size_t N0 = (size_t)by * 256;
  int row8 = wid * 8 + (lane >> 3);
  int sl = lane & 7;
  int fr = lane & 15, fq = lane >> 4;
  f32x4 acc[4][4] = {};
  f16x8 a[8], b[8];

  const char* AB = (const char*)Af;
  const char* WB = (const char*)Wf;
  const size_t aoff0 = (M0 + row8) * 4096 + (size_t)sl * 16;
  const size_t aoff1 = (M0 + 64 + row8) * 4096 + (size_t)sl * 16;
  const size_t woff0 = (N0 + row8) * 4096 + (size_t)sl * 16;
  const size_t woff1 = (N0 + 64 + row8) * 4096 + (size_t)sl * 16;
  const size_t woff2 = (N0 + 128 + row8) * 4096 + (size_t)sl * 16;
  const size_t woff3 = (N0 + 192 + row8) * 4096 + (size_t)sl * 16;

#define STAGE_ALL(dst, s) do {                                                     \
    int koff_ = (s) << 7;                                                          \
    char* l_ = (char*)(dst) + wid * 1024;                                          \
    gload16(AB + aoff0 + koff_, l_);                                               \
    gload16(AB + aoff1 + koff_, l_ + 8192);                                        \
    gload16(WB + woff0 + koff_, l_ + 16384);                                       \
    gload16(WB + woff1 + koff_, l_ + 24576);                                       \
    gload16(WB + woff2 + koff_, l_ + 32768);                                       \
    gload16(WB + woff3 + koff_, l_ + 40960);                                       \
  } while (0)

#define LOADG(buf, g) do {                                                         \
    const f16* bA_ = (const f16*)(buf);                                            \
    const f16* bB_ = bA_ + 8192;                                                   \
    int cg_ = (g) * 4 + fq;                                                        \
    _Pragma("unroll") for (int mi = 0; mi < 4; ++mi) {                             \
      int m_ = wr * 64 + mi * 16 + fr;                                             \
      a[(g) * 4 + mi] = *(const f16x8*)(bA_ + m_ * 64 + ((cg_ ^ (m_ & 7)) << 3));  \
    }                                                                              \
    _Pragma("unroll") for (int ni = 0; ni < 4; ++ni) {                             \
      int n_ = wc * 64 + ni * 16 + fr;                                             \
      b[(g) * 4 + ni] = *(const f16x8*)(bB_ + n_ * 64 + ((cg_ ^ (n_ & 7)) << 3));  \
    }                                                                              \
  } while (0)

#define STEP(rdbuf, stbuf, kt) do {                                                \
    if ((kt) < 31) { WAIT_VM6; } else { WAIT_VM0; }                                \
    __builtin_amdgcn_s_barrier();                                                  \
    if ((kt) <= 29) STAGE_ALL(stbuf, (kt) + 2);                                    \
    LOADG(rdbuf, 0);                                                               \
    __builtin_amdgcn_sched_barrier(0);                                             \
    LOADG(rdbuf, 1);                                                               \
    WAIT_LGKM8;                                                                    \
    __builtin_amdgcn_sched_barrier(0);                                             \
    __builtin_amdgcn_s_setprio(1);                                                 \
    _Pragma("unroll") for (int mi = 0; mi < 4; ++mi)                               \
      _Pragma("unroll") for (int ni = 0; ni < 4; ++ni)                             \
        acc[mi][ni] = __builtin_amdgcn_mfma_f32_16x16x32_f16(a[mi], b[ni], acc[mi][ni], 0, 0, 0); \
    WAIT_LGKM0;                                                                    \
    __builtin_amdgcn_sched_barrier(0);                                             \
    _Pragma("unroll") for (int mi = 0; mi < 4; ++mi)                               \
      _Pragma("unroll") for (int ni = 0; ni < 4; ++ni)                             \
        acc[mi][ni] = __builtin_amdgcn_mfma_f32_16x16x32_f16(a[4 + mi], b[4 + ni], acc[mi][ni], 0, 0, 0); \
    __builtin_amdgcn_s_setprio(0);                                                 \
  } while (0)

  STAGE_ALL(&S[0][0], 0);
  STAGE_ALL(&S[1][0], 1);
  for (int base = 0; base < 30; base += 3) {
    STEP(&S[0][0], &S[2][0], base);
    STEP(&S[1][0], &S[0][0], base + 1);
    STEP(&S[2][0], &S[1][0], base + 2);
  }
  STEP(&S[0][0], &S[2][0], 30);
  STEP(&S[1][0], &S[0][0], 31);
#undef STEP
#undef LOADG
#undef STAGE_ALL

  const float* bias = by ? beta_b : gamma_b;
  f16* outb = by ? betaFh : gammaFh;
#pragma unroll
  for (int mi = 0; mi < 4; ++mi) {
    int hwb = wr * 64 + mi * 16 + fq * 4;
#pragma unroll
    for (int ni = 0; ni < 4; ++ni) {
      int o = wc * 64 + ni * 16 + fr;
      float bb = bias[o];
      f32x4 v = acc[mi][ni];
      f16x4 w;
      w[0] = (f16)fmaxf(v[0] + bb, 0.f);
      w[1] = (f16)fmaxf(v[1] + bb, 0.f);
      w[2] = (f16)fmaxf(v[2] + bb, 0.f);
      w[3] = (f16)fmaxf(v[3] + bb, 0.f);
      *(f16x4*)(outb + (size_t)bx * 32768 + (size_t)o * 128 + hwb) = w;
    }
  }
}

// ---------------- kM1: theta (512) + ta both-gates hh/4 (256) + Gs (256) ----------------
// Arena LDS 36.9KB -> 4 blocks/CU; 1024 blocks = 4/CU exactly co-resident.
__global__ __launch_bounds__(256) void kM1(const float* __restrict__ vect, const float* __restrict__ thwT,
                                           float* __restrict__ P,
                                           const float* __restrict__ embed, const float* __restrict__ tteT,
                                           const float* __restrict__ tte_b, const float* __restrict__ te_w,
                                           float* __restrict__ Sta,
                                           const f16* __restrict__ gammaFh, const f16* __restrict__ betaFh,
                                           float* __restrict__ Gs0, float* __restrict__ Gs1) {
  __shared__ __align__(16) char arena[36992];
  int bid = blockIdx.x;
  int t = threadIdx.x;
  if (bid < 512) {                       // ---- theta GEMV ----
    float* V = (float*)arena;            // 512 floats
    int bt = bid & 127, kq = bid >> 7;
    const float* src = vect + (size_t)bt * 2048 + kq * 512;
    if (t < 128) *(float4*)(V + t * 4) = *(const float4*)(src + t * 4);
    __syncthreads();
    const float* wp = thwT + (size_t)kq * 512 * 256 + t;
    float acc = 0.f;
#pragma unroll 8
    for (int c = 0; c < 512; ++c)
      acc = fmaf(wp[(size_t)c * 256], V[c], acc);
    P[((size_t)kq * 128 + bt) * 256 + t] = acc;
    return;
  }
  if (bid < 768) {                       // ---- ta, both gates, 32-hw slice ----
    float* E = (float*)arena;            // [256][32] = 32KB
    float* Red2 = (float*)(arena + 32768);  // [2][16][32] = 4KB
    int i = bid - 512;
    int n = i & 63, hq = i >> 6;         // hw quarter
    int b = n >> 2, p = n & 3;
    const float* eA = embed + (size_t)(b * 8 + 2 * p) * 16384 + hq * 32;
    const float* eB = eA + 16384;
    for (int r = 0; r < 4; ++r) {
      int f = r * 256 + t;
      int ch = f >> 3, q = (f & 7) * 4;
      *(float4*)(E + ch * 32 + q) = *(const float4*)(eA + (size_t)ch * 128 + q);
    }
    for (int r = 0; r < 4; ++r) {
      int f = r * 256 + t;
      int ch = f >> 3, q = (f & 7) * 4;
      *(float4*)(E + (128 + ch) * 32 + q) = *(const float4*)(eB + (size_t)ch * 128 + q);
    }
    __syncthreads();
    int ty = t >> 4, tx = t & 15;        // 16 o-groups x 16 (2 hw each)
    float acc0[8][2] = {}, acc1[8][2] = {};
    for (int c = 0; c < 256; ++c) {
      float w8a[8], w8b[8];
      *(float4*)w8a = *(const float4*)(tteT + (size_t)c * 128 + ty * 8);
      *(float4*)(w8a + 4) = *(const float4*)(tteT + (size_t)c * 128 + ty * 8 + 4);
      int c2 = c ^ 128;
      *(float4*)w8b = *(const float4*)(tteT + (size_t)c2 * 128 + ty * 8);
      *(float4*)(w8b + 4) = *(const float4*)(tteT + (size_t)c2 * 128 + ty * 8 + 4);
      float2 g = *(const float2*)(E + c * 32 + tx * 2);
      for (int ii = 0; ii < 8; ++ii) {
        acc0[ii][0] = fmaf(w8a[ii], g.x, acc0[ii][0]);
        acc0[ii][1] = fmaf(w8a[ii], g.y, acc0[ii][1]);
        acc1[ii][0] = fmaf(w8b[ii], g.x, acc1[ii][0]);
        acc1[ii][1] = fmaf(w8b[ii], g.y, acc1[ii][1]);
      }
    }
    float par0[2] = {0.f, 0.f}, par1[2] = {0.f, 0.f};
    for (int ii = 0; ii < 8; ++ii) {
      int o = ty * 8 + ii;
      float tb = tte_b[o], tw = te_w[o];
      for (int j = 0; j < 2; ++j) {
        par0[j] += tw * fmaxf(acc0[ii][j] + tb, 0.f);
        par1[j] += tw * fmaxf(acc1[ii][j] + tb, 0.f);
      }
    }
    for (int j = 0; j < 2; ++j) {
      Red2[0 * 512 + ty * 32 + tx * 2 + j] = par0[j];
      Red2[1 * 512 + ty * 32 + tx * 2 + j] = par1[j];
    }
    __syncthreads();
    if (t < 64) {
      int g = t >> 5, tt = t & 31;
      float s = 0.f;
      for (int q = 0; q < 16; ++q) s += Red2[g * 512 + q * 32 + tt];
      Sta[(size_t)g * 8192 + n * 128 + hq * 32 + tt] = s;
    }
    return;
  }
  // ---- Gs: per (n, which, th): Gs[s][t-half] = sum_c A[c][s]*B[c][t] (f16 in) ----
  float* As = (float*)arena;             // [16][128] = 8KB
  float* Bs = (float*)(arena + 8192);    // [16][64]  = 4KB
  int i = bid - 768;
  int n = i & 63, which = (i >> 6) & 1, th = (i >> 7) & 1;
  int b = n >> 2, p = n & 3;
  int tg = 2 * p + which;
  int tb = 2 * p + 1 - which;
  const f16* A = gammaFh + (size_t)(b * 8 + tg) * 32768;
  const f16* Bm = betaFh + (size_t)(b * 8 + tb) * 32768;
  float* out = (which ? Gs1 : Gs0) + (size_t)n * 16384;
  int ty = t >> 4, tx = t & 15;
  float acc[8][4] = {};
  for (int c0 = 0; c0 < 256; c0 += 16) {
    {
      int cc = t >> 4, col8 = (t & 15) * 8;
      f16x8 v = *(const f16x8*)(A + (size_t)(c0 + cc) * 128 + col8);
      for (int j = 0; j < 8; ++j) As[cc * 128 + col8 + j] = (float)v[j];
    }
    if (t < 128) {
      int cc = t >> 3, col8 = (t & 7) * 8;
      f16x8 v = *(const f16x8*)(Bm + (size_t)(c0 + cc) * 128 + th * 64 + col8);
      for (int j = 0; j < 8; ++j) Bs[cc * 64 + col8 + j] = (float)v[j];
    }
    __syncthreads();
    for (int cc = 0; cc < 16; ++cc) {
      float a8[8];
      *(float4*)a8 = *(const float4*)(As + cc * 128 + ty * 8);
      *(float4*)(a8 + 4) = *(const float4*)(As + cc * 128 + ty * 8 + 4);
      float4 b4 = *(const float4*)(Bs + cc * 64 + tx * 4);
      for (int ii = 0; ii < 8; ++ii) {
        acc[ii][0] = fmaf(a8[ii], b4.x, acc[ii][0]);
        acc[ii][1] = fmaf(a8[ii], b4.y, acc[ii][1]);
        acc[ii][2] = fmaf(a8[ii], b4.z, acc[ii][2]);
        acc[ii][3] = fmaf(a8[ii], b4.w, acc[ii][3]);
      }
    }
    __syncthreads();
  }
  for (int ii = 0; ii < 8; ++ii) {
    *(float4*)(out + (size_t)(ty * 8 + ii) * 128 + th * 64 + tx * 4) =
        make_float4(acc[ii][0], acc[ii][1], acc[ii][2], acc[ii][3]);
  }
}

// ---------------- kM2: gj (256, G1c read direct from L2) + whole-MLP-per-bp (64) ----------------
__global__ __launch_bounds__(256) void kM2(const float* __restrict__ Gs0, const float* __restrict__ Gs1,
                                           const float* __restrict__ ggT, const float* __restrict__ gg_b,
                                           const float* __restrict__ te_w, float* __restrict__ Sgj,
                                           const float* __restrict__ P, const float* __restrict__ thb,
                                           const float* __restrict__ w1T, const float* __restrict__ b1,
                                           const float* __restrict__ w2T, const float* __restrict__ b2,
                                           float* __restrict__ p00, float* __restrict__ p01) {
  __shared__ __align__(16) char arena[37248];
  int bid = blockIdx.x;
  int t = threadIdx.x;
  if (bid < 256) {                       // ---- gj ----
    float* G0h = (float*)arena;          // [64][129] = 33KB
    float* Red = (float*)(arena + 33024); // [16][64] = 4KB
    int n = bid & 63, gate = (bid >> 6) & 1, hh = (bid >> 7) & 1;
    const float* srcT = (gate == 0 ? Gs0 : Gs1) + (size_t)n * 16384;
    const float* srcC = (gate == 0 ? Gs1 : Gs0) + (size_t)n * 16384 + hh * 64;
    for (int r = 0; r < 8; ++r) {
      int f = r * 256 + t;
      int hwl = f >> 5, c4 = (f & 31) * 4;
      float4 v = *(const float4*)(srcT + (size_t)(hh * 64 + hwl) * 128 + c4);
      G0h[hwl * 129 + c4 + 0] = v.x;
      G0h[hwl * 129 + c4 + 1] = v.y;
      G0h[hwl * 129 + c4 + 2] = v.z;
      G0h[hwl * 129 + c4 + 3] = v.w;
    }
    __syncthreads();
    int ty = t >> 4, tx = t & 15;
    float acc[8][4] = {};
    for (int c = 0; c < 128; ++c) {      // first half: J[c][hw] = Gs_gate[hw][c]
      float w8[8];
      *(float4*)w8 = *(const float4*)(ggT + (size_t)c * 128 + ty * 8);
      *(float4*)(w8 + 4) = *(const float4*)(ggT + (size_t)c * 128 + ty * 8 + 4);
      float g4[4];
      for (int j = 0; j < 4; ++j) g4[j] = G0h[(tx * 4 + j) * 129 + c];
      for (int ii = 0; ii < 8; ++ii)
        for (int j = 0; j < 4; ++j)
          acc[ii][j] = fmaf(w8[ii], g4[j], acc[ii][j]);
    }
    for (int c = 0; c < 128; ++c) {      // second half: direct L2 read of Gs_other
      float w8[8];
      *(float4*)w8 = *(const float4*)(ggT + (size_t)(128 + c) * 128 + ty * 8);
      *(float4*)(w8 + 4) = *(const float4*)(ggT + (size_t)(128 + c) * 128 + ty * 8 + 4);
      float4 g = *(const float4*)(srcC + (size_t)c * 128 + tx * 4);
      for (int ii = 0; ii < 8; ++ii) {
        acc[ii][0] = fmaf(w8[ii], g.x, acc[ii][0]);
        acc[ii][1] = fmaf(w8[ii], g.y, acc[ii][1]);
        acc[ii][2] = fmaf(w8[ii], g.z, acc[ii][2]);
        acc[ii][3] = fmaf(w8[ii], g.w, acc[ii][3]);
      }
    }
    float par[4] = {0.f, 0.f, 0.f, 0.f};
    for (int ii = 0; ii < 8; ++ii) {
      int o = ty * 8 + ii;
      float gb = gg_b[o], tw = te_w[128 + o];
      for (int j = 0; j < 4; ++j)
        par[j] += tw * fmaxf(acc[ii][j] + gb, 0.f);
    }
    for (int j = 0; j < 4; ++j) Red[ty * 64 + tx * 4 + j] = par[j];
    __syncthreads();
    if (t < 64) {
      float s = 0.f;
      for (int g = 0; g < 16; ++g) s += Red[g * 64 + t];
      Sgj[(size_t)gate * 8192 + n * 128 + hh * 64 + t] = s;
    }
    return;
  }
  // ---- whole MLP for one bp: theta-reduce -> layer1 -> layer2+sigmoid ----
  float* x0 = (float*)arena;
  float* x1 = x0 + 256;
  float* h1a = x0 + 512;
  float* h1b = x0 + 768;
  int bp = bid - 256;
  int b = bp >> 2, p = bp & 3;
  int bt0 = b * 8 + 2 * p, bt1 = bt0 + 1;
  {
    float a0 = 0.f, a1 = 0.f;
    for (int q = 0; q < 4; ++q) {
      a0 += P[((size_t)q * 128 + bt0) * 256 + t];
      a1 += P[((size_t)q * 128 + bt1) * 256 + t];
    }
    float tb = thb[t];
    x0[t] = fmaxf(a0 + tb, 0.f);
    x1[t] = fmaxf(a1 + tb, 0.f);
  }
  __syncthreads();
  {
    float aa = 0.f, ab = 0.f;
    const float* wp = w1T + t;
#pragma unroll 4
    for (int k = 0; k < 256; ++k) {
      float w = wp[(size_t)k * 256];
      aa = fmaf(w, x0[k], aa);
      ab = fmaf(w, x1[k], ab);
    }
#pragma unroll 4
    for (int k = 0; k < 256; ++k) {
      float w = wp[(size_t)(256 + k) * 256];
      aa = fmaf(w, x1[k], aa);
      ab = fmaf(w, x0[k], ab);
    }
    float bb = b1[t];
    h1a[t] = fmaxf(aa + bb, 0.f);
    h1b[t] = fmaxf(ab + bb, 0.f);
  }
  __syncthreads();
  for (int r = 0; r < 8; ++r) {
    int ch = r * 256 + t;
    float sa = 0.f, sb = 0.f;
#pragma unroll 4
    for (int k = 0; k < 256; ++k) {
      float w = w2T[(size_t)k * 2048 + ch];
      sa = fmaf(w, h1a[k], sa);
      sb = fmaf(w, h1b[k], sb);
    }
    p00[(size_t)bp * 2048 + ch] = sigmoidf_(sa + b2[ch]);
    p01[(size_t)bp * 2048 + ch] = sigmoidf_(sb + b2[ch]);
  }
}

// ---------------- final elementwise (gate sigmoid fused) ----------------
__global__ __launch_bounds__(256) void kFinal(const float* __restrict__ featmap, const float* __restrict__ p00,
                                              const float* __restrict__ p01, const float* __restrict__ Sta,
                                              const float* __restrict__ Sgj, const float* __restrict__ te_s,
                                              const float* __restrict__ te_b, float* __restrict__ out) {
  int fid = blockIdx.x * 256 + threadIdx.x;
  int h4 = (fid & 31) * 4;
  int c = (fid >> 5) & 2047;
  int bp = fid >> 16;
  int b = bp >> 2, p = bp & 3;
  float ga = p00[(size_t)bp * 2048 + c];
  float gb = p01[(size_t)bp * 2048 + c];
  float ts = te_s[0], tbv = te_b[0];
  float4 sa0 = *(const float4*)(Sta + (size_t)bp * 128 + h4);
  float4 sg0 = *(const float4*)(Sgj + (size_t)bp * 128 + h4);
  float4 sa1 = *(const float4*)(Sta + 8192 + (size_t)bp * 128 + h4);
  float4 sg1 = *(const float4*)(Sgj + 8192 + (size_t)bp * 128 + h4);
  float4 pa4, pb4;
  pa4.x = sigmoidf_(ts * (sa0.x + sg0.x) + tbv);
  pa4.y = sigmoidf_(ts * (sa0.y + sg0.y) + tbv);
  pa4.z = sigmoidf_(ts * (sa0.z + sg0.z) + tbv);
  pa4.w = sigmoidf_(ts * (sa0.w + sg0.w) + tbv);
  pb4.x = sigmoidf_(ts * (sa1.x + sg1.x) + tbv);
  pb4.y = sigmoidf_(ts * (sa1.y + sg1.y) + tbv);
  pb4.z = sigmoidf_(ts * (sa1.z + sg1.z) + tbv);
  pb4.w = sigmoidf_(ts * (sa1.w + sg1.w) + tbv);
  const float* f0 = featmap + (size_t)(b * 8 + 2 * p) * 262144 + (size_t)c * 128 + h4;
  const float* f1 = f0 + 262144;
  float4 v0 = *(const float4*)f0;
  float4 v1 = *(const float4*)f1;
  float4 o4;
  float r;
  r = fmaxf(ga * pa4.x * v0.x + gb * pb4.x * v1.x, 0.f); o4.x = r * r;
  r = fmaxf(ga * pa4.y * v0.y + gb * pb4.y * v1.y, 0.f); o4.y = r * r;
  r = fmaxf(ga * pa4.z * v0.z + gb * pb4.z * v1.z, 0.f); o4.z = r * r;
  r = fmaxf(ga * pa4.w * v0.w + gb * pb4.w * v1.w, 0.f); o4.w = r * r;
  *(float4*)(out + (size_t)fid * 4) = o4;
}

extern "C" void kernel_launch(void* const* d_in, const int* in_sizes, int n_in,
                              void* d_out, int out_size, void* d_ws, size_t ws_size,
                              hipStream_t stream) {
  (void)in_sizes; (void)n_in; (void)out_size; (void)ws_size;
  const float* featmap    = (const float*)d_in[0];
  const float* re_featmap = (const float*)d_in[1];
  const float* vect       = (const float*)d_in[2];
  const float* embed      = (const float*)d_in[3];
  const float* gamma_w    = (const float*)d_in[4];
  const float* gamma_s    = (const float*)d_in[5];
  const float* gamma_b    = (const float*)d_in[6];
  const float* beta_w     = (const float*)d_in[7];
  const float* beta_s     = (const float*)d_in[8];
  const float* beta_b     = (const float*)d_in[9];
  const float* gg_w       = (const float*)d_in[10];
  const float* gg_s       = (const float*)d_in[11];
  const float* gg_b       = (const float*)d_in[12];
  const float* tte_w      = (const float*)d_in[13];
  const float* tte_s      = (const float*)d_in[14];
  const float* tte_b      = (const float*)d_in[15];
  const float* te_w       = (const float*)d_in[16];
  const float* te_s       = (const float*)d_in[17];
  const float* te_b       = (const float*)d_in[18];
  const float* theta_w    = (const float*)d_in[19];
  const float* theta_b    = (const float*)d_in[20];
  const float* cp_w1      = (const float*)d_in[21];
  const float* cp_b1      = (const float*)d_in[22];
  const float* cp_w2      = (const float*)d_in[23];
  const float* cp_b2      = (const float*)d_in[24];
  float* out = (float*)d_out;

  char* w = (char*)d_ws;
  f16* Af  = (f16*)w;   w += (size_t)16384 * 2048 * 2;
  f16* Wf  = (f16*)w;   w += (size_t)512 * 2048 * 2;
  f16* gammaFh = (f16*)w; w += (size_t)128 * 256 * 128 * 2;
  f16* betaFh  = (f16*)w; w += (size_t)128 * 256 * 128 * 2;
  float* Gs0    = (float*)w; w += (size_t)64 * 128 * 128 * 4;
  float* Gs1    = (float*)w; w += (size_t)64 * 128 * 128 * 4;
  float* ggT    = (float*)w; w += (size_t)256 * 128 * 4;
  float* tteT   = (float*)w; w += (size_t)256 * 128 * 4;
  float* thwT   = (float*)w; w += (size_t)2048 * 256 * 4;
  float* w1T    = (float*)w; w += (size_t)512 * 256 * 4;
  float* w2T    = (float*)w; w += (size_t)256 * 2048 * 4;
  float* P      = (float*)w; w += (size_t)4 * 128 * 256 * 4;
  float* Sta    = (float*)w; w += (size_t)2 * 64 * 128 * 4;
  float* Sgj    = (float*)w; w += (size_t)2 * 64 * 128 * 4;
  float* p00    = (float*)w; w += (size_t)64 * 2048 * 4;
  float* p01    = (float*)w; w += (size_t)64 * 2048 * 4;

  kPP<<<9008, 256, 0, stream>>>(re_featmap, Af,
                                gamma_w, gamma_s, beta_w, beta_s, gg_w, gg_s, tte_w, tte_s,
                                theta_w, cp_w1, cp_w2, Wf, ggT, tteT, thwT, w1T, w2T);
  kGemm8<<<256, 512, 0, stream>>>(Af, Wf, gamma_b, beta_b, gammaFh, betaFh);
  kM1<<<1024, 256, 0, stream>>>(vect, thwT, P, embed, tteT, tte_b, te_w, Sta,
                                gammaFh, betaFh, Gs0, Gs1);
  kM2<<<320, 256, 0, stream>>>(Gs0, Gs1, ggT, gg_b, te_w, Sgj,
                               P, theta_b, w1T, cp_b1, w2T, cp_b2, p00, p01);
  kFinal<<<16384, 256, 0, stream>>>(featmap, p00, p01, Sta, Sgj, te_s, te_b, out);
}

// Round 12
// 248.279 us; speedup vs baseline: 1.5847x; 1.5847x over previous
//
#include <hip/hip_runtime.h>
#include <stdint.h>

// Shapes: B=16 T=8 C=2048 H=16 W=8 -> C8=256 C4=512 HW=128 NP=4
// NIMG = B*T = 128, M = NIMG*HW = 16384, Ncat = 2*C8 = 512, K = 2048

typedef _Float16 f16;
typedef _Float16 f16x4 __attribute__((ext_vector_type(4)));
typedef _Float16 f16x8 __attribute__((ext_vector_type(8)));
typedef float f32x4 __attribute__((ext_vector_type(4)));

typedef const void __attribute__((address_space(1)))* gptr1;
typedef void __attribute__((address_space(3)))* lptr3;

__device__ __forceinline__ void gload16(const void* g, void* l) {
  __builtin_amdgcn_global_load_lds((gptr1)g, (lptr3)l, 16, 0, 0);
}

__device__ __forceinline__ float sigmoidf_(float x) { return 1.f / (1.f + expf(-x)); }

#define WAIT_VM6 asm volatile("s_waitcnt vmcnt(6)" ::: "memory")
#define WAIT_VM0 asm volatile("s_waitcnt vmcnt(0)" ::: "memory")
#define WAIT_LGKM8 asm volatile("s_waitcnt lgkmcnt(8)" ::: "memory")
#define WAIT_LGKM0 asm volatile("s_waitcnt lgkmcnt(0)" ::: "memory")

// ---------------- Merged Prep + P1 ----------------
// bid < 8192: P1 transpose re_featmap (64k x 64hw tiles, 16.6KB LDS -> 8 blocks/CU)
//             -> A[m][k] f16, chunk-XOR pre-swizzled.
// 8192 <= bid < 8704: Wf = [gamma_w*gs ; beta_w*bs] f16, pre-swizzled.
// bid >= 8704: LDS-tiled 64x64 transposes (thwT, w2T, w1T, ggT, tteT).
__global__ __launch_bounds__(256) void kPP(const float* __restrict__ x,
                                           f16* __restrict__ Af,
                                           const float* __restrict__ gw, const float* __restrict__ gs,
                                           const float* __restrict__ bw, const float* __restrict__ bs,
                                           const float* __restrict__ gg_w, const float* __restrict__ gg_s,
                                           const float* __restrict__ tte_w, const float* __restrict__ tte_s,
                                           const float* __restrict__ thw, const float* __restrict__ w1,
                                           const float* __restrict__ w2,
                                           f16* __restrict__ Wf,
                                           float* __restrict__ ggT, float* __restrict__ tteT,
                                           float* __restrict__ thwT, float* __restrict__ w1T,
                                           float* __restrict__ w2T) {
  __shared__ __align__(16) char shmem[64 * 65 * 4];
  int t = threadIdx.x;
  int bid = blockIdx.x;
  if (bid < 8192) {
    float (*L)[65] = (float(*)[65])shmem;
    int n = bid >> 6;
    int kc = (bid >> 1) & 31;
    int hh = bid & 1;
    int k0 = kc * 64;
    const float* src = x + (size_t)n * 262144 + (size_t)k0 * 128 + hh * 64;
    for (int r = 0; r < 4; ++r) {
      int f = r * 256 + t;             // 1024 float4 = 64k x 64hw
      int kk = f >> 4, c4 = (f & 15) * 4;
      float4 v = *(const float4*)(src + (size_t)kk * 128 + c4);
      L[kk][c4 + 0] = v.x; L[kk][c4 + 1] = v.y; L[kk][c4 + 2] = v.z; L[kk][c4 + 3] = v.w;
    }
    __syncthreads();
    for (int r = 0; r < 2; ++r) {
      int id = r * 256 + t;            // 512 = 64 hw * 8 chunks
      int hw = id >> 3, c = id & 7;
      int cs = c ^ (hw & 7);           // ((hh*64+hw)&7 == hw&7)
      f16x8 h8;
      for (int j = 0; j < 8; ++j)
        h8[j] = (f16)L[cs * 8 + j][hw];
      size_t m = (size_t)n * 128 + hh * 64 + hw;
      size_t ob = m * 2048 + (size_t)k0 + (size_t)c * 8;
      *(f16x8*)(Af + ob) = h8;
    }
    return;
  }
  if (bid < 8704) {                  // Wf: 512 o * 256 chunks
    int id = (bid - 8192) * 256 + t;
    int o = id >> 8, cch = id & 255;
    float s; const float* row;
    if (o < 256) { s = gs[o]; row = gw + (size_t)o * 2048; }
    else         { s = bs[o - 256]; row = bw + (size_t)(o - 256) * 2048; }
    int kb = cch >> 3, sub = cch & 7;
    int subd = sub ^ (o & 7);
    f16x8 h8;
    for (int j = 0; j < 8; ++j)
      h8[j] = (f16)(row[cch * 8 + j] * s);
    size_t ob = (size_t)o * 2048 + (size_t)kb * 64 + (size_t)subd * 8;
    *(f16x8*)(Wf + ob) = h8;
    return;
  }
  // tiled transposes: out[C][R] from src[R][C], optional per-src-row scale
  float (*TL)[65] = (float(*)[65])shmem;
  int tb = bid - 8704;
  const float* src; float* dst; const float* scale = nullptr; int R, C;
  if (tb < 128)      { src = thw;   dst = thwT; R = 256;  C = 2048; }
  else if (tb < 256) { tb -= 128; src = w2;  dst = w2T;  R = 2048; C = 256; }
  else if (tb < 288) { tb -= 256; src = w1;  dst = w1T;  R = 256;  C = 512; }
  else if (tb < 296) { tb -= 288; src = gg_w;  dst = ggT;  scale = gg_s;  R = 128; C = 256; }
  else               { tb -= 296; src = tte_w; dst = tteT; scale = tte_s; R = 128; C = 256; }
  int tpc = C >> 6;
  int r0 = (tb / tpc) * 64, c0 = (tb % tpc) * 64;
  int i16 = t >> 4, j4 = (t & 15) * 4;
  for (int s = 0; s < 4; ++s) {
    int i = i16 + s * 16;
    float4 v = *(const float4*)(src + (size_t)(r0 + i) * C + c0 + j4);
    TL[i][j4 + 0] = v.x; TL[i][j4 + 1] = v.y; TL[i][j4 + 2] = v.z; TL[i][j4 + 3] = v.w;
  }
  __syncthreads();
  for (int s = 0; s < 4; ++s) {
    int j = i16 + s * 16;
    float4 w;
    w.x = TL[j4 + 0][j]; w.y = TL[j4 + 1][j]; w.z = TL[j4 + 2][j]; w.w = TL[j4 + 3][j];
    if (scale) {
      w.x *= scale[r0 + j4 + 0]; w.y *= scale[r0 + j4 + 1];
      w.z *= scale[r0 + j4 + 2]; w.w *= scale[r0 + j4 + 3];
    }
    *(float4*)(dst + (size_t)(c0 + j) * R + r0 + j4) = w;
  }
}

// ---------------- Stage A GEMM: C[16384][512] = A_f16 * Wf^T, 32 K-steps of 64 ----
// BM=128 BN=256 BK=64, 512 threads = 8 waves (2M x 4N), 64x64/wave.
// 3 rotating LDS buffers (48KB each), stage kt+2 during kt, counted vmcnt(6).
// Per step: vmcnt(6) -> barrier -> STAGE(kt+2) -> 8 ds_read -> 8 ds_read ->
//           lgkm(8) -> 16 MFMA -> lgkm(0) -> 16 MFMA.  (round-7 schedule)
__global__ __launch_bounds__(512, 2) void kGemm8(const f16* __restrict__ Af, const f16* __restrict__ Wf,
                                                 const float* __restrict__ gamma_b, const float* __restrict__ beta_b,
                                                 f16* __restrict__ gammaFh, f16* __restrict__ betaFh) {
  __shared__ __align__(16) f16 S[3][24576];   // per buffer: A[0:8192], B[8192:24576] (f16 idx)
  int t = threadIdx.x;
  int lane = t & 63, wid = t >> 6;
  int wr = wid >> 2, wc = wid & 3;
  // XCD swizzle pairing (bx, by=0) and (bx, by=1) on the same XCD:
  int bid = blockIdx.x;
  int bx = (bid & 7) * 16 + (bid >> 4);
  int by = (bid >> 3) & 1;
  size_t M0 = (size_t)bx * 128;
  size_t N0 = (size_t)by * 256;
  int row8 = wid * 8 + (lane >> 3);
  int sl = lane & 7;
  int fr = lane & 15, fq = lane >> 4;
  f32x4 acc[4][4] = {};
  f16x8 a[8], b[8];

  const char* AB = (const char*)Af;
  const char* WB = (const char*)Wf;
  const size_t aoff0 = (M0 + row8) * 4096 + (size_t)sl * 16;
  const size_t aoff1 = (M0 + 64 + row8) * 4096 + (size_t)sl * 16;
  const size_t woff0 = (N0 + row8) * 4096 + (size_t)sl * 16;
  const size_t woff1 = (N0 + 64 + row8) * 4096 + (size_t)sl * 16;
  const size_t woff2 = (N0 + 128 + row8) * 4096 + (size_t)sl * 16;
  const size_t woff3 = (N0 + 192 + row8) * 4096 + (size_t)sl * 16;

#define STAGE_ALL(dst, s) do {                                                     \
    int koff_ = (s) << 7;                                                          \
    char* l_ = (char*)(dst) + wid * 1024;                                          \
    gload16(AB + aoff0 + koff_, l_);                                               \
    gload16(AB + aoff1 + koff_, l_ + 8192);                                        \
    gload16(WB + woff0 + koff_, l_ + 16384);                                       \
    gload16(WB + woff1 + koff_, l_ + 24576);                                       \
    gload16(WB + woff2 + koff_, l_ + 32768);                                       \
    gload16(WB + woff3 + koff_, l_ + 40960);                                       \
  } while (0)

#define LOADG(buf, g) do {                                                         \
    const f16* bA_ = (const f16*)(buf);                                            \
    const f16* bB_ = bA_ + 8192;                                                   \
    int cg_ = (g) * 4 + fq;                                                        \
    _Pragma("unroll") for (int mi = 0; mi < 4; ++mi) {                             \
      int m_ = wr * 64 + mi * 16 + fr;                                             \
      a[(g) * 4 + mi] = *(const f16x8*)(bA_ + m_ * 64 + ((cg_ ^ (m_ & 7)) << 3));  \
    }                                                                              \
    _Pragma("unroll") for (int ni = 0; ni < 4; ++ni) {                             \
      int n_ = wc * 64 + ni * 16 + fr;                                             \
      b[(g) * 4 + ni] = *(const f16x8*)(bB_ + n_ * 64 + ((cg_ ^ (n_ & 7)) << 3));  \
    }                                                                              \
  } while (0)

#define STEP(rdbuf, stbuf, kt) do {                                                \
    if ((kt) < 31) { WAIT_VM6; } else { WAIT_VM0; }                                \
    __builtin_amdgcn_s_barrier();                                                  \
    if ((kt) <= 29) STAGE_ALL(stbuf, (kt) + 2);                                    \
    LOADG(rdbuf, 0);                                                               \
    __builtin_amdgcn_sched_barrier(0);                                             \
    LOADG(rdbuf, 1);                                                               \
    WAIT_LGKM8;                                                                    \
    __builtin_amdgcn_sched_barrier(0);                                             \
    __builtin_amdgcn_s_setprio(1);                                                 \
    _Pragma("unroll") for (int mi = 0; mi < 4; ++mi)                               \
      _Pragma("unroll") for (int ni = 0; ni < 4; ++ni)                             \
        acc[mi][ni] = __builtin_amdgcn_mfma_f32_16x16x32_f16(a[mi], b[ni], acc[mi][ni], 0, 0, 0); \
    WAIT_LGKM0;                                                                    \
    __builtin_amdgcn_sched_barrier(0);                                             \
    _Pragma("unroll") for (int mi = 0; mi < 4; ++mi)                               \
      _Pragma("unroll") for (int ni = 0; ni < 4; ++ni)                             \
        acc[mi][ni] = __builtin_amdgcn_mfma_f32_16x16x32_f16(a[4 + mi], b[4 + ni], acc[mi][ni], 0, 0, 0); \
    __builtin_amdgcn_s_setprio(0);                                                 \
  } while (0)

  STAGE_ALL(&S[0][0], 0);
  STAGE_ALL(&S[1][0], 1);
  for (int base = 0; base < 30; base += 3) {
    STEP(&S[0][0], &S[2][0], base);
    STEP(&S[1][0], &S[0][0], base + 1);
    STEP(&S[2][0], &S[1][0], base + 2);
  }
  STEP(&S[0][0], &S[2][0], 30);
  STEP(&S[1][0], &S[0][0], 31);
#undef STEP
#undef LOADG
#undef STAGE_ALL

  // epilogue: +bias, relu, store f16 to gammaFh/betaFh[n][o][hw]
  const float* bias = by ? beta_b : gamma_b;
  f16* outb = by ? betaFh : gammaFh;
#pragma unroll
  for (int mi = 0; mi < 4; ++mi) {
    int hwb = wr * 64 + mi * 16 + fq * 4;     // C/D: row = (lane>>4)*4 + reg
#pragma unroll
    for (int ni = 0; ni < 4; ++ni) {
      int o = wc * 64 + ni * 16 + fr;         // C/D: col = lane&15
      float bb = bias[o];
      f32x4 v = acc[mi][ni];
      f16x4 w;
      w[0] = (f16)fmaxf(v[0] + bb, 0.f);
      w[1] = (f16)fmaxf(v[1] + bb, 0.f);
      w[2] = (f16)fmaxf(v[2] + bb, 0.f);
      w[3] = (f16)fmaxf(v[3] + bb, 0.f);
      *(f16x4*)(outb + (size_t)bx * 32768 + (size_t)o * 128 + hwb) = w;
    }
  }
}

// ---------------- Merged Theta2 + Ta ----------------
// bid < 512: theta K-split GEMV. bid >= 512: ta-gate partial.
__global__ __launch_bounds__(256) void kTT(const float* __restrict__ vect, const float* __restrict__ thwT,
                                           float* __restrict__ P,
                                           const float* __restrict__ embed, const float* __restrict__ tteT,
                                           const float* __restrict__ tte_b, const float* __restrict__ te_w,
                                           float* __restrict__ Sta) {
  __shared__ float V[512];
  __shared__ __align__(16) float E[256 * 64];
  __shared__ float Red[16 * 64];
  int bid = blockIdx.x;
  int t = threadIdx.x;
  if (bid < 512) {
    int bt = bid & 127, kq = bid >> 7;
    const float* src = vect + (size_t)bt * 2048 + kq * 512;
    if (t < 128) *(float4*)(V + t * 4) = *(const float4*)(src + t * 4);
    __syncthreads();
    const float* wp = thwT + (size_t)kq * 512 * 256 + t;
    float acc = 0.f;
#pragma unroll 8
    for (int c = 0; c < 512; ++c)
      acc = fmaf(wp[(size_t)c * 256], V[c], acc);
    P[((size_t)kq * 128 + bt) * 256 + t] = acc;
    return;
  }
  int i = bid - 512;
  int n = i & 63, gate = (i >> 6) & 1, hh = (i >> 7) & 1;
  int b = n >> 2, p = n & 3;
  const float* eA = embed + (size_t)(b * 8 + 2 * p + gate) * 16384 + hh * 64;
  const float* eB = embed + (size_t)(b * 8 + 2 * p + 1 - gate) * 16384 + hh * 64;
  for (int r = 0; r < 8; ++r) {
    int f = r * 256 + t;
    int ch = f >> 4, q = (f & 15) * 4;
    *(float4*)(E + ch * 64 + q) = *(const float4*)(eA + (size_t)ch * 128 + q);
  }
  for (int r = 0; r < 8; ++r) {
    int f = r * 256 + t;
    int ch = f >> 4, q = (f & 15) * 4;
    *(float4*)(E + (128 + ch) * 64 + q) = *(const float4*)(eB + (size_t)ch * 128 + q);
  }
  __syncthreads();
  int ty = t >> 4, tx = t & 15;
  float acc[8][4] = {};
  for (int c = 0; c < 256; ++c) {
    float w8[8];
    *(float4*)w8 = *(const float4*)(tteT + (size_t)c * 128 + ty * 8);
    *(float4*)(w8 + 4) = *(const float4*)(tteT + (size_t)c * 128 + ty * 8 + 4);
    float4 g = *(const float4*)(E + c * 64 + tx * 4);
    for (int ii = 0; ii < 8; ++ii) {
      acc[ii][0] = fmaf(w8[ii], g.x, acc[ii][0]);
      acc[ii][1] = fmaf(w8[ii], g.y, acc[ii][1]);
      acc[ii][2] = fmaf(w8[ii], g.z, acc[ii][2]);
      acc[ii][3] = fmaf(w8[ii], g.w, acc[ii][3]);
    }
  }
  float par[4] = {0.f, 0.f, 0.f, 0.f};
  for (int ii = 0; ii < 8; ++ii) {
    int o = ty * 8 + ii;
    float tb = tte_b[o], tw = te_w[o];
    for (int j = 0; j < 4; ++j)
      par[j] += tw * fmaxf(acc[ii][j] + tb, 0.f);
  }
  for (int j = 0; j < 4; ++j) Red[ty * 64 + tx * 4 + j] = par[j];
  __syncthreads();
  if (t < 64) {
    float s = 0.f;
    for (int g = 0; g < 16; ++g) s += Red[g * 64 + t];
    Sta[(size_t)gate * 8192 + n * 128 + hh * 64 + t] = s;
  }
}

// ---------------- Merged MlpA + Gs (gammaF/betaF are f16) ----------------
__global__ __launch_bounds__(256) void kAG(const float* __restrict__ P, const float* __restrict__ thb,
                                           const float* __restrict__ w1T, const float* __restrict__ b1,
                                           float* __restrict__ h1,
                                           const f16* __restrict__ gammaFh, const f16* __restrict__ betaFh,
                                           float* __restrict__ Gs0, float* __restrict__ Gs1) {
  __shared__ float x0[256], x1[256];
  __shared__ float ra[256], rb[256];
  __shared__ __align__(16) float As[16 * 128];
  __shared__ __align__(16) float Bs[16 * 64];
  int bid = blockIdx.x;
  int t = threadIdx.x;
  if (bid < 256) {
    int bp = bid & 63, och = bid >> 6;
    int b = bp >> 2, p = bp & 3;
    int bt0 = b * 8 + 2 * p, bt1 = bt0 + 1;
    {
      float a0 = 0.f, a1 = 0.f;
      for (int q = 0; q < 4; ++q) {
        a0 += P[((size_t)q * 128 + bt0) * 256 + t];
        a1 += P[((size_t)q * 128 + bt1) * 256 + t];
      }
      float tb = thb[t];
      x0[t] = fmaxf(a0 + tb, 0.f);
      x1[t] = fmaxf(a1 + tb, 0.f);
    }
    __syncthreads();
    int o = och * 64 + (t & 63);
    int ks = t >> 6;
    const float* xa = (ks < 2) ? x0 : x1;
    const float* xb = (ks < 2) ? x1 : x0;
    int kbase = ks * 128;
    int xoff = (ks < 2) ? kbase : kbase - 256;
    float aa = 0.f, ab = 0.f;
#pragma unroll 8
    for (int ii = 0; ii < 128; ++ii) {
      float w = w1T[(size_t)(kbase + ii) * 256 + o];
      aa = fmaf(w, xa[xoff + ii], aa);
      ab = fmaf(w, xb[xoff + ii], ab);
    }
    ra[t] = aa;
    rb[t] = ab;
    __syncthreads();
    if (t < 64) {
      float sa = ra[t] + ra[64 + t] + ra[128 + t] + ra[192 + t];
      float sb = rb[t] + rb[64 + t] + rb[128 + t] + rb[192 + t];
      float bb = b1[o];
      h1[((size_t)bp * 2) * 256 + o] = fmaxf(sa + bb, 0.f);
      h1[((size_t)bp * 2 + 1) * 256 + o] = fmaxf(sb + bb, 0.f);
    }
    return;
  }
  int i = bid - 256;
  int n = i & 63, which = (i >> 6) & 1, th = (i >> 7) & 1;
  int b = n >> 2, p = n & 3;
  int tg = 2 * p + which;
  int tb = 2 * p + 1 - which;
  const f16* A = gammaFh + (size_t)(b * 8 + tg) * 32768;
  const f16* Bm = betaFh + (size_t)(b * 8 + tb) * 32768;
  float* out = (which ? Gs1 : Gs0) + (size_t)n * 16384;
  int ty = t >> 4, tx = t & 15;
  float acc[8][4] = {};
  for (int c0 = 0; c0 < 256; c0 += 16) {
    {
      int cc = t >> 4, col8 = (t & 15) * 8;   // A: 16 rows x 128 cols, 8 f16/thread
      f16x8 v = *(const f16x8*)(A + (size_t)(c0 + cc) * 128 + col8);
      for (int j = 0; j < 8; ++j) As[cc * 128 + col8 + j] = (float)v[j];
    }
    if (t < 128) {                            // B: 16 rows x 64 cols, 8 f16/thread
      int cc = t >> 3, col8 = (t & 7) * 8;
      f16x8 v = *(const f16x8*)(Bm + (size_t)(c0 + cc) * 128 + th * 64 + col8);
      for (int j = 0; j < 8; ++j) Bs[cc * 64 + col8 + j] = (float)v[j];
    }
    __syncthreads();
    for (int cc = 0; cc < 16; ++cc) {
      float a8[8];
      *(float4*)a8 = *(const float4*)(As + cc * 128 + ty * 8);
      *(float4*)(a8 + 4) = *(const float4*)(As + cc * 128 + ty * 8 + 4);
      float4 b4 = *(const float4*)(Bs + cc * 64 + tx * 4);
      for (int ii = 0; ii < 8; ++ii) {
        acc[ii][0] = fmaf(a8[ii], b4.x, acc[ii][0]);
        acc[ii][1] = fmaf(a8[ii], b4.y, acc[ii][1]);
        acc[ii][2] = fmaf(a8[ii], b4.z, acc[ii][2]);
        acc[ii][3] = fmaf(a8[ii], b4.w, acc[ii][3]);
      }
    }
    __syncthreads();
  }
  for (int ii = 0; ii < 8; ++ii) {
    *(float4*)(out + (size_t)(ty * 8 + ii) * 128 + th * 64 + tx * 4) =
        make_float4(acc[ii][0], acc[ii][1], acc[ii][2], acc[ii][3]);
  }
}

// ---------------- Merged MlpB + Gj ----------------
__global__ __launch_bounds__(256) void kBG(const float* __restrict__ h1, const float* __restrict__ w2T,
                                           const float* __restrict__ b2,
                                           float* __restrict__ p00, float* __restrict__ p01,
                                           const float* __restrict__ Gs0, const float* __restrict__ Gs1,
                                           const float* __restrict__ ggT, const float* __restrict__ gg_b,
                                           const float* __restrict__ te_w, float* __restrict__ Sgj) {
  __shared__ float ha[256], hb[256];
  __shared__ float G0h[64 * 129];
  __shared__ __align__(16) float G1c[128 * 64];
  __shared__ float Red[16 * 64];
  int bid = blockIdx.x;
  int t = threadIdx.x;
  if (bid < 512) {
    int bp = bid & 63, chc = bid >> 6;
    ha[t] = h1[((size_t)bp * 2) * 256 + t];
    hb[t] = h1[((size_t)bp * 2 + 1) * 256 + t];
    __syncthreads();
    int ch = chc * 256 + t;
    float sa = 0.f, sb = 0.f;
#pragma unroll 8
    for (int k = 0; k < 256; ++k) {
      float w = w2T[(size_t)k * 2048 + ch];
      sa = fmaf(w, ha[k], sa);
      sb = fmaf(w, hb[k], sb);
    }
    p00[(size_t)bp * 2048 + ch] = sigmoidf_(sa + b2[ch]);
    p01[(size_t)bp * 2048 + ch] = sigmoidf_(sb + b2[ch]);
    return;
  }
  int i = bid - 512;
  int n = i & 63, gate = (i >> 6) & 1, hh = (i >> 7) & 1;
  const float* srcT = (gate == 0 ? Gs0 : Gs1) + (size_t)n * 16384;
  const float* srcC = (gate == 0 ? Gs1 : Gs0) + (size_t)n * 16384;
  for (int r = 0; r < 8; ++r) {
    int f = r * 256 + t;
    int hwl = f >> 5, c4 = (f & 31) * 4;
    float4 v = *(const float4*)(srcT + (size_t)(hh * 64 + hwl) * 128 + c4);
    G0h[hwl * 129 + c4 + 0] = v.x;
    G0h[hwl * 129 + c4 + 1] = v.y;
    G0h[hwl * 129 + c4 + 2] = v.z;
    G0h[hwl * 129 + c4 + 3] = v.w;
  }
  for (int r = 0; r < 8; ++r) {
    int f = r * 256 + t;
    int c = f >> 4, q = (f & 15) * 4;
    *(float4*)(G1c + c * 64 + q) = *(const float4*)(srcC + (size_t)c * 128 + hh * 64 + q);
  }
  __syncthreads();
  int ty = t >> 4, tx = t & 15;
  float acc[8][4] = {};
  for (int c = 0; c < 128; ++c) {
    float w8[8];
    *(float4*)w8 = *(const float4*)(ggT + (size_t)c * 128 + ty * 8);
    *(float4*)(w8 + 4) = *(const float4*)(ggT + (size_t)c * 128 + ty * 8 + 4);
    float g4[4];
    for (int j = 0; j < 4; ++j) g4[j] = G0h[(tx * 4 + j) * 129 + c];
    for (int ii = 0; ii < 8; ++ii)
      for (int j = 0; j < 4; ++j)
        acc[ii][j] = fmaf(w8[ii], g4[j], acc[ii][j]);
  }
  for (int c = 0; c < 128; ++c) {
    float w8[8];
    *(float4*)w8 = *(const float4*)(ggT + (size_t)(128 + c) * 128 + ty * 8);
    *(float4*)(w8 + 4) = *(const float4*)(ggT + (size_t)(128 + c) * 128 + ty * 8 + 4);
    float4 g = *(const float4*)(G1c + c * 64 + tx * 4);
    for (int ii = 0; ii < 8; ++ii) {
      acc[ii][0] = fmaf(w8[ii], g.x, acc[ii][0]);
      acc[ii][1] = fmaf(w8[ii], g.y, acc[ii][1]);
      acc[ii][2] = fmaf(w8[ii], g.z, acc[ii][2]);
      acc[ii][3] = fmaf(w8[ii], g.w, acc[ii][3]);
    }
  }
  float par[4] = {0.f, 0.f, 0.f, 0.f};
  for (int ii = 0; ii < 8; ++ii) {
    int o = ty * 8 + ii;
    float gb = gg_b[o], tw = te_w[128 + o];
    for (int j = 0; j < 4; ++j)
      par[j] += tw * fmaxf(acc[ii][j] + gb, 0.f);
  }
  for (int j = 0; j < 4; ++j) Red[ty * 64 + tx * 4 + j] = par[j];
  __syncthreads();
  if (t < 64) {
    float s = 0.f;
    for (int g = 0; g < 16; ++g) s += Red[g * 64 + t];
    Sgj[(size_t)gate * 8192 + n * 128 + hh * 64 + t] = s;
  }
}

// ---------------- final elementwise (gate sigmoid fused): out = relu(p00*pa*f0 + p01*pb*f1)^2 ----
__global__ __launch_bounds__(256) void kFinal(const float* __restrict__ featmap, const float* __restrict__ p00,
                                              const float* __restrict__ p01, const float* __restrict__ Sta,
                                              const float* __restrict__ Sgj, const float* __restrict__ te_s,
                                              const float* __restrict__ te_b, float* __restrict__ out) {
  int fid = blockIdx.x * 256 + threadIdx.x;  // 4,194,304 float4 tasks
  int h4 = (fid & 31) * 4;
  int c = (fid >> 5) & 2047;
  int bp = fid >> 16;
  int b = bp >> 2, p = bp & 3;
  float ga = p00[(size_t)bp * 2048 + c];
  float gb = p01[(size_t)bp * 2048 + c];
  float ts = te_s[0], tbv = te_b[0];
  float4 sa0 = *(const float4*)(Sta + (size_t)bp * 128 + h4);
  float4 sg0 = *(const float4*)(Sgj + (size_t)bp * 128 + h4);
  float4 sa1 = *(const float4*)(Sta + 8192 + (size_t)bp * 128 + h4);
  float4 sg1 = *(const float4*)(Sgj + 8192 + (size_t)bp * 128 + h4);
  float4 pa4, pb4;
  pa4.x = sigmoidf_(ts * (sa0.x + sg0.x) + tbv);
  pa4.y = sigmoidf_(ts * (sa0.y + sg0.y) + tbv);
  pa4.z = sigmoidf_(ts * (sa0.z + sg0.z) + tbv);
  pa4.w = sigmoidf_(ts * (sa0.w + sg0.w) + tbv);
  pb4.x = sigmoidf_(ts * (sa1.x + sg1.x) + tbv);
  pb4.y = sigmoidf_(ts * (sa1.y + sg1.y) + tbv);
  pb4.z = sigmoidf_(ts * (sa1.z + sg1.z) + tbv);
  pb4.w = sigmoidf_(ts * (sa1.w + sg1.w) + tbv);
  const float* f0 = featmap + (size_t)(b * 8 + 2 * p) * 262144 + (size_t)c * 128 + h4;
  const float* f1 = f0 + 262144;
  float4 v0 = *(const float4*)f0;
  float4 v1 = *(const float4*)f1;
  float4 o4;
  float r;
  r = fmaxf(ga * pa4.x * v0.x + gb * pb4.x * v1.x, 0.f); o4.x = r * r;
  r = fmaxf(ga * pa4.y * v0.y + gb * pb4.y * v1.y, 0.f); o4.y = r * r;
  r = fmaxf(ga * pa4.z * v0.z + gb * pb4.z * v1.z, 0.f); o4.z = r * r;
  r = fmaxf(ga * pa4.w * v0.w + gb * pb4.w * v1.w, 0.f); o4.w = r * r;
  *(float4*)(out + (size_t)fid * 4) = o4;
}

extern "C" void kernel_launch(void* const* d_in, const int* in_sizes, int n_in,
                              void* d_out, int out_size, void* d_ws, size_t ws_size,
                              hipStream_t stream) {
  (void)in_sizes; (void)n_in; (void)out_size; (void)ws_size;
  const float* featmap    = (const float*)d_in[0];
  const float* re_featmap = (const float*)d_in[1];
  const float* vect       = (const float*)d_in[2];
  const float* embed      = (const float*)d_in[3];
  const float* gamma_w    = (const float*)d_in[4];
  const float* gamma_s    = (const float*)d_in[5];
  const float* gamma_b    = (const float*)d_in[6];
  const float* beta_w     = (const float*)d_in[7];
  const float* beta_s     = (const float*)d_in[8];
  const float* beta_b     = (const float*)d_in[9];
  const float* gg_w       = (const float*)d_in[10];
  const float* gg_s       = (const float*)d_in[11];
  const float* gg_b       = (const float*)d_in[12];
  const float* tte_w      = (const float*)d_in[13];
  const float* tte_s      = (const float*)d_in[14];
  const float* tte_b      = (const float*)d_in[15];
  const float* te_w       = (const float*)d_in[16];
  const float* te_s       = (const float*)d_in[17];
  const float* te_b       = (const float*)d_in[18];
  const float* theta_w    = (const float*)d_in[19];
  const float* theta_b    = (const float*)d_in[20];
  const float* cp_w1      = (const float*)d_in[21];
  const float* cp_b1      = (const float*)d_in[22];
  const float* cp_w2      = (const float*)d_in[23];
  const float* cp_b2      = (const float*)d_in[24];
  float* out = (float*)d_out;

  char* w = (char*)d_ws;
  f16* Af  = (f16*)w;   w += (size_t)16384 * 2048 * 2;
  f16* Wf  = (f16*)w;   w += (size_t)512 * 2048 * 2;
  f16* gammaFh = (f16*)w; w += (size_t)128 * 256 * 128 * 2;
  f16* betaFh  = (f16*)w; w += (size_t)128 * 256 * 128 * 2;
  float* Gs0    = (float*)w; w += (size_t)64 * 128 * 128 * 4;
  float* Gs1    = (float*)w; w += (size_t)64 * 128 * 128 * 4;
  float* ggT    = (float*)w; w += (size_t)256 * 128 * 4;
  float* tteT   = (float*)w; w += (size_t)256 * 128 * 4;
  float* thwT   = (float*)w; w += (size_t)2048 * 256 * 4;
  float* w1T    = (float*)w; w += (size_t)512 * 256 * 4;
  float* w2T    = (float*)w; w += (size_t)256 * 2048 * 4;
  float* P      = (float*)w; w += (size_t)4 * 128 * 256 * 4;
  float* h1     = (float*)w; w += (size_t)64 * 2 * 256 * 4;
  float* Sta    = (float*)w; w += (size_t)2 * 64 * 128 * 4;
  float* Sgj    = (float*)w; w += (size_t)2 * 64 * 128 * 4;
  float* p00    = (float*)w; w += (size_t)64 * 2048 * 4;
  float* p01    = (float*)w; w += (size_t)64 * 2048 * 4;

  kPP<<<9008, 256, 0, stream>>>(re_featmap, Af,
                                gamma_w, gamma_s, beta_w, beta_s, gg_w, gg_s, tte_w, tte_s,
                                theta_w, cp_w1, cp_w2, Wf, ggT, tteT, thwT, w1T, w2T);
  kGemm8<<<256, 512, 0, stream>>>(Af, Wf, gamma_b, beta_b, gammaFh, betaFh);
  kTT<<<768, 256, 0, stream>>>(vect, thwT, P, embed, tteT, tte_b, te_w, Sta);
  kAG<<<512, 256, 0, stream>>>(P, theta_b, w1T, cp_b1, h1, gammaFh, betaFh, Gs0, Gs1);
  kBG<<<768, 256, 0, stream>>>(h1, w2T, cp_b2, p00, p01, Gs0, Gs1, ggT, gg_b, te_w, Sgj);
  kFinal<<<16384, 256, 0, stream>>>(featmap, p00, p01, Sta, Sgj, te_s, te_b, out);
}

// Round 13
// 240.101 us; speedup vs baseline: 1.6387x; 1.0341x over previous
//
#include <hip/hip_runtime.h>
#include <stdint.h>

// Shapes: B=16 T=8 C=2048 H=16 W=8 -> C8=256 C4=512 HW=128 NP=4
// NIMG = B*T = 128, M = NIMG*HW = 16384, Ncat = 2*C8 = 512, K = 2048

typedef _Float16 f16;
typedef _Float16 f16x2 __attribute__((ext_vector_type(2)));
typedef _Float16 f16x4 __attribute__((ext_vector_type(4)));
typedef _Float16 f16x8 __attribute__((ext_vector_type(8)));
typedef float f32x4 __attribute__((ext_vector_type(4)));

typedef const void __attribute__((address_space(1)))* gptr1;
typedef void __attribute__((address_space(3)))* lptr3;

__device__ __forceinline__ void gload16(const void* g, void* l) {
  __builtin_amdgcn_global_load_lds((gptr1)g, (lptr3)l, 16, 0, 0);
}

__device__ __forceinline__ float sigmoidf_(float x) { return 1.f / (1.f + expf(-x)); }

#define WAIT_VM8 asm volatile("s_waitcnt vmcnt(8)" ::: "memory")
#define WAIT_VM0 asm volatile("s_waitcnt vmcnt(0)" ::: "memory")
#define WAIT_LGKM8 asm volatile("s_waitcnt lgkmcnt(8)" ::: "memory")
#define WAIT_LGKM0 asm volatile("s_waitcnt lgkmcnt(0)" ::: "memory")
#define SBAR __builtin_amdgcn_s_barrier()
#define SCHED0 __builtin_amdgcn_sched_barrier(0)

// ---------------- Prep: Wf f16 pre-swizzled + LDS-tiled weight transposes ----------------
// bid < 512: Wf = [gamma_w*gs ; beta_w*bs] f16, chunk-XOR pre-swizzled.
// bid >= 512: 64x64 tiled transposes (thwT, w2T, w1T, ggT, tteT).
__global__ __launch_bounds__(256) void kPP(const float* __restrict__ gw, const float* __restrict__ gs,
                                           const float* __restrict__ bw, const float* __restrict__ bs,
                                           const float* __restrict__ gg_w, const float* __restrict__ gg_s,
                                           const float* __restrict__ tte_w, const float* __restrict__ tte_s,
                                           const float* __restrict__ thw, const float* __restrict__ w1,
                                           const float* __restrict__ w2,
                                           f16* __restrict__ Wf,
                                           float* __restrict__ ggT, float* __restrict__ tteT,
                                           float* __restrict__ thwT, float* __restrict__ w1T,
                                           float* __restrict__ w2T) {
  __shared__ __align__(16) float TL[64][65];
  int t = threadIdx.x;
  int bid = blockIdx.x;
  if (bid < 512) {                   // Wf: 512 o * 256 chunks
    int id = bid * 256 + t;
    int o = id >> 8, cch = id & 255;
    float s; const float* row;
    if (o < 256) { s = gs[o]; row = gw + (size_t)o * 2048; }
    else         { s = bs[o - 256]; row = bw + (size_t)(o - 256) * 2048; }
    int kb = cch >> 3, sub = cch & 7;
    int subd = sub ^ (o & 7);
    f16x8 h8;
    for (int j = 0; j < 8; ++j)
      h8[j] = (f16)(row[cch * 8 + j] * s);
    size_t ob = (size_t)o * 2048 + (size_t)kb * 64 + (size_t)subd * 8;
    *(f16x8*)(Wf + ob) = h8;
    return;
  }
  // tiled transposes: out[C][R] from src[R][C], optional per-src-row scale
  int tb = bid - 512;
  const float* src; float* dst; const float* scale = nullptr; int R, C;
  if (tb < 128)      { src = thw;   dst = thwT; R = 256;  C = 2048; }
  else if (tb < 256) { tb -= 128; src = w2;  dst = w2T;  R = 2048; C = 256; }
  else if (tb < 288) { tb -= 256; src = w1;  dst = w1T;  R = 256;  C = 512; }
  else if (tb < 296) { tb -= 288; src = gg_w;  dst = ggT;  scale = gg_s;  R = 128; C = 256; }
  else               { tb -= 296; src = tte_w; dst = tteT; scale = tte_s; R = 128; C = 256; }
  int tpc = C >> 6;
  int r0 = (tb / tpc) * 64, c0 = (tb % tpc) * 64;
  int i16 = t >> 4, j4 = (t & 15) * 4;
  for (int s = 0; s < 4; ++s) {
    int i = i16 + s * 16;
    float4 v = *(const float4*)(src + (size_t)(r0 + i) * C + c0 + j4);
    TL[i][j4 + 0] = v.x; TL[i][j4 + 1] = v.y; TL[i][j4 + 2] = v.z; TL[i][j4 + 3] = v.w;
  }
  __syncthreads();
  for (int s = 0; s < 4; ++s) {
    int j = i16 + s * 16;
    float4 w;
    w.x = TL[j4 + 0][j]; w.y = TL[j4 + 1][j]; w.z = TL[j4 + 2][j]; w.w = TL[j4 + 3][j];
    if (scale) {
      w.x *= scale[r0 + j4 + 0]; w.y *= scale[r0 + j4 + 1];
      w.z *= scale[r0 + j4 + 2]; w.w *= scale[r0 + j4 + 3];
    }
    *(float4*)(dst + (size_t)(c0 + j) * R + r0 + j4) = w;
  }
}

// ---------------- Stage A GEMM with fused A-transpose ----------------
// C[16384][512] = A_f16 * Wf^T, A converted fp32->f16 in-kernel from re_featmap.
// BM=128 BN=256 BK=64, 512 threads = 8 waves (2M x 4N), 64x64/wave.
// 3 rotating LDS buffers; per step: barrier -> issue A-loads(t+2)+W-gloads(t+2) ->
// vmcnt(8) -> convert+ds_write A(t+1)->nxt -> frag reads(cur) -> lgkm(8) -> 16 MFMA
// -> lgkm(0) -> 16 MFMA.  A reg banks alternate by step parity (named, unrolled x6).
__global__ __launch_bounds__(512, 2) void kGemm8(const float* __restrict__ X, const f16* __restrict__ Wf,
                                                 const float* __restrict__ gamma_b, const float* __restrict__ beta_b,
                                                 f16* __restrict__ gammaFh, f16* __restrict__ betaFh) {
  __shared__ __align__(16) f16 S[3][24576];   // per buffer: A[0:8192], B[8192:24576] (f16 idx)
  int t = threadIdx.x;
  int lane = t & 63, wid = t >> 6;
  int wr = wid >> 2, wc = wid & 3;
  int bid = blockIdx.x;
  int bx = (bid & 7) * 16 + (bid >> 4);      // XCD pairing: by=0/1 share A on one XCD
  int by = (bid >> 3) & 1;
  size_t N0 = (size_t)by * 256;
  int row8 = wid * 8 + (lane >> 3);
  int sl = lane & 7;
  int fr = lane & 15, fq = lane >> 4;
  f32x4 acc[4][4] = {};
  f16x8 a[8], b[8];
  float4 ar0[4], ar1[4];                     // A staging register banks (parity)

  // A source: re_featmap[bx][k][hw] fp32
  const float* Xb = X + (size_t)bx * 262144;
  int kkB = 2 * ((lane >> 3) + ((wid >> 2) << 3));   // even, 0..30
  int hw4 = ((lane & 7) << 2) + ((wid & 3) << 5);    // 0..124
  // LDS write f16-indices for (r: k-half, j: hw sub) -- matches fragment-read swizzle
  int wo[2][4];
#pragma unroll
  for (int r = 0; r < 2; ++r) {
    int kk = kkB + 32 * r;
    int cg = kk >> 3, kp = kk & 7;
#pragma unroll
    for (int j = 0; j < 4; ++j) {
      int hw = hw4 + j;
      wo[r][j] = hw * 64 + ((cg ^ (hw & 7)) << 3) + kp;
    }
  }

  const char* WB = (const char*)Wf;
  const size_t woff0 = (N0 + row8) * 4096 + (size_t)sl * 16;
  const size_t woff1 = (N0 + 64 + row8) * 4096 + (size_t)sl * 16;
  const size_t woff2 = (N0 + 128 + row8) * 4096 + (size_t)sl * 16;
  const size_t woff3 = (N0 + 192 + row8) * 4096 + (size_t)sl * 16;

#define AISSUE(bank, s) do {                                                       \
    const float* p_ = Xb + ((s) * 64 + kkB) * 128 + hw4;                           \
    bank[0] = *(const float4*)(p_);                                                \
    bank[1] = *(const float4*)(p_ + 128);                                          \
    bank[2] = *(const float4*)(p_ + 4096);                                         \
    bank[3] = *(const float4*)(p_ + 4096 + 128);                                   \
  } while (0)

#define WSTAGE(dst, s) do {                                                        \
    int koff_ = (s) << 7;                                                          \
    char* l_ = (char*)(dst) + 16384 + wid * 1024;                                  \
    gload16(WB + woff0 + koff_, l_);                                               \
    gload16(WB + woff1 + koff_, l_ + 8192);                                        \
    gload16(WB + woff2 + koff_, l_ + 16384);                                       \
    gload16(WB + woff3 + koff_, l_ + 24576);                                       \
  } while (0)

#define AWRITE(bank, dst) do {                                                     \
    f16* ad_ = (f16*)(dst);                                                        \
    _Pragma("unroll") for (int r_ = 0; r_ < 2; ++r_) {                             \
      const float* lo_ = (const float*)&bank[2 * r_];                              \
      const float* hi_ = (const float*)&bank[2 * r_ + 1];                          \
      _Pragma("unroll") for (int j_ = 0; j_ < 4; ++j_) {                           \
        f16x2 h_;                                                                  \
        h_[0] = (f16)lo_[j_];                                                      \
        h_[1] = (f16)hi_[j_];                                                      \
        *(f16x2*)(ad_ + wo[r_][j_]) = h_;                                          \
      }                                                                            \
    }                                                                              \
  } while (0)

#define LOADG(buf, g) do {                                                         \
    const f16* bA_ = (const f16*)(buf);                                            \
    const f16* bB_ = bA_ + 8192;                                                   \
    int cg_ = (g) * 4 + fq;                                                        \
    _Pragma("unroll") for (int mi = 0; mi < 4; ++mi) {                             \
      int m_ = wr * 64 + mi * 16 + fr;                                             \
      a[(g) * 4 + mi] = *(const f16x8*)(bA_ + m_ * 64 + ((cg_ ^ (m_ & 7)) << 3));  \
    }                                                                              \
    _Pragma("unroll") for (int ni = 0; ni < 4; ++ni) {                             \
      int n_ = wc * 64 + ni * 16 + fr;                                             \
      b[(g) * 4 + ni] = *(const f16x8*)(bB_ + n_ * 64 + ((cg_ ^ (n_ & 7)) << 3));  \
    }                                                                              \
  } while (0)

#define MFMA_G(g) do {                                                             \
    _Pragma("unroll") for (int mi = 0; mi < 4; ++mi)                               \
      _Pragma("unroll") for (int ni = 0; ni < 4; ++ni)                             \
        acc[mi][ni] = __builtin_amdgcn_mfma_f32_16x16x32_f16(                      \
            a[(g) * 4 + mi], b[(g) * 4 + ni], acc[mi][ni], 0, 0, 0);               \
  } while (0)

  // STEP s: cur=s%3, nxt=(s+1)%3, n2=(s+2)%3; issue bank = ar[s&1]; write bank = ar[(s+1)&1]
#define STEP(cur, nxt, n2, s, BI, BW) do {                                         \
    SBAR;                                                                          \
    if ((s) <= 29) { AISSUE(BI, (s) + 2); WSTAGE(n2, (s) + 2); }                   \
    SCHED0;                                                                        \
    if ((s) <= 29) { WAIT_VM8; } else { WAIT_VM0; }                                \
    SCHED0;                                                                        \
    if ((s) <= 30) AWRITE(BW, nxt);                                                \
    SCHED0;                                                                        \
    LOADG(cur, 0);                                                                 \
    SCHED0;                                                                        \
    LOADG(cur, 1);                                                                 \
    WAIT_LGKM8;                                                                    \
    SCHED0;                                                                        \
    __builtin_amdgcn_s_setprio(1);                                                 \
    MFMA_G(0);                                                                     \
    WAIT_LGKM0;                                                                    \
    SCHED0;                                                                        \
    MFMA_G(1);                                                                     \
    __builtin_amdgcn_s_setprio(0);                                                 \
  } while (0)

  // prologue: A(0)->ar0/buf0, A(1)->ar1/buf1
  AISSUE(ar0, 0); WSTAGE(&S[0][0], 0);
  SCHED0;
  AISSUE(ar1, 1); WSTAGE(&S[1][0], 1);
  SCHED0;
  WAIT_VM8;                 // A(0),W(0) done
  SCHED0;
  AWRITE(ar0, &S[0][0]);
  WAIT_LGKM0;

  for (int base = 0; base < 30; base += 6) {
    STEP(&S[0][0], &S[1][0], &S[2][0], base + 0, ar0, ar1);
    STEP(&S[1][0], &S[2][0], &S[0][0], base + 1, ar1, ar0);
    STEP(&S[2][0], &S[0][0], &S[1][0], base + 2, ar0, ar1);
    STEP(&S[0][0], &S[1][0], &S[2][0], base + 3, ar1, ar0);
    STEP(&S[1][0], &S[2][0], &S[0][0], base + 4, ar0, ar1);
    STEP(&S[2][0], &S[0][0], &S[1][0], base + 5, ar1, ar0);
  }
  STEP(&S[0][0], &S[1][0], &S[2][0], 30, ar0, ar1);   // writes A(31)->buf1, no issue
  STEP(&S[1][0], &S[2][0], &S[0][0], 31, ar1, ar0);   // reads buf1, no write
#undef STEP
#undef MFMA_G
#undef LOADG
#undef AWRITE
#undef WSTAGE
#undef AISSUE

  // epilogue: +bias, relu, store f16 to gammaFh/betaFh[n][o][hw]
  const float* bias = by ? beta_b : gamma_b;
  f16* outb = by ? betaFh : gammaFh;
#pragma unroll
  for (int mi = 0; mi < 4; ++mi) {
    int hwb = wr * 64 + mi * 16 + fq * 4;     // C/D: row = (lane>>4)*4 + reg
#pragma unroll
    for (int ni = 0; ni < 4; ++ni) {
      int o = wc * 64 + ni * 16 + fr;         // C/D: col = lane&15
      float bb = bias[o];
      f32x4 v = acc[mi][ni];
      f16x4 w;
      w[0] = (f16)fmaxf(v[0] + bb, 0.f);
      w[1] = (f16)fmaxf(v[1] + bb, 0.f);
      w[2] = (f16)fmaxf(v[2] + bb, 0.f);
      w[3] = (f16)fmaxf(v[3] + bb, 0.f);
      *(f16x4*)(outb + (size_t)bx * 32768 + (size_t)o * 128 + hwb) = w;
    }
  }
}

// ---------------- Merged Theta2 + Ta ----------------
__global__ __launch_bounds__(256) void kTT(const float* __restrict__ vect, const float* __restrict__ thwT,
                                           float* __restrict__ P,
                                           const float* __restrict__ embed, const float* __restrict__ tteT,
                                           const float* __restrict__ tte_b, const float* __restrict__ te_w,
                                           float* __restrict__ Sta) {
  __shared__ float V[512];
  __shared__ __align__(16) float E[256 * 64];
  __shared__ float Red[16 * 64];
  int bid = blockIdx.x;
  int t = threadIdx.x;
  if (bid < 512) {
    int bt = bid & 127, kq = bid >> 7;
    const float* src = vect + (size_t)bt * 2048 + kq * 512;
    if (t < 128) *(float4*)(V + t * 4) = *(const float4*)(src + t * 4);
    __syncthreads();
    const float* wp = thwT + (size_t)kq * 512 * 256 + t;
    float acc = 0.f;
#pragma unroll 8
    for (int c = 0; c < 512; ++c)
      acc = fmaf(wp[(size_t)c * 256], V[c], acc);
    P[((size_t)kq * 128 + bt) * 256 + t] = acc;
    return;
  }
  int i = bid - 512;
  int n = i & 63, gate = (i >> 6) & 1, hh = (i >> 7) & 1;
  int b = n >> 2, p = n & 3;
  const float* eA = embed + (size_t)(b * 8 + 2 * p + gate) * 16384 + hh * 64;
  const float* eB = embed + (size_t)(b * 8 + 2 * p + 1 - gate) * 16384 + hh * 64;
  for (int r = 0; r < 8; ++r) {
    int f = r * 256 + t;
    int ch = f >> 4, q = (f & 15) * 4;
    *(float4*)(E + ch * 64 + q) = *(const float4*)(eA + (size_t)ch * 128 + q);
  }
  for (int r = 0; r < 8; ++r) {
    int f = r * 256 + t;
    int ch = f >> 4, q = (f & 15) * 4;
    *(float4*)(E + (128 + ch) * 64 + q) = *(const float4*)(eB + (size_t)ch * 128 + q);
  }
  __syncthreads();
  int ty = t >> 4, tx = t & 15;
  float acc[8][4] = {};
  for (int c = 0; c < 256; ++c) {
    float w8[8];
    *(float4*)w8 = *(const float4*)(tteT + (size_t)c * 128 + ty * 8);
    *(float4*)(w8 + 4) = *(const float4*)(tteT + (size_t)c * 128 + ty * 8 + 4);
    float4 g = *(const float4*)(E + c * 64 + tx * 4);
    for (int ii = 0; ii < 8; ++ii) {
      acc[ii][0] = fmaf(w8[ii], g.x, acc[ii][0]);
      acc[ii][1] = fmaf(w8[ii], g.y, acc[ii][1]);
      acc[ii][2] = fmaf(w8[ii], g.z, acc[ii][2]);
      acc[ii][3] = fmaf(w8[ii], g.w, acc[ii][3]);
    }
  }
  float par[4] = {0.f, 0.f, 0.f, 0.f};
  for (int ii = 0; ii < 8; ++ii) {
    int o = ty * 8 + ii;
    float tb = tte_b[o], tw = te_w[o];
    for (int j = 0; j < 4; ++j)
      par[j] += tw * fmaxf(acc[ii][j] + tb, 0.f);
  }
  for (int j = 0; j < 4; ++j) Red[ty * 64 + tx * 4 + j] = par[j];
  __syncthreads();
  if (t < 64) {
    float s = 0.f;
    for (int g = 0; g < 16; ++g) s += Red[g * 64 + t];
    Sta[(size_t)gate * 8192 + n * 128 + hh * 64 + t] = s;
  }
}

// ---------------- Merged MlpA + Gs (gammaF/betaF are f16) ----------------
__global__ __launch_bounds__(256) void kAG(const float* __restrict__ P, const float* __restrict__ thb,
                                           const float* __restrict__ w1T, const float* __restrict__ b1,
                                           float* __restrict__ h1,
                                           const f16* __restrict__ gammaFh, const f16* __restrict__ betaFh,
                                           float* __restrict__ Gs0, float* __restrict__ Gs1) {
  __shared__ float x0[256], x1[256];
  __shared__ float ra[256], rb[256];
  __shared__ __align__(16) float As[16 * 128];
  __shared__ __align__(16) float Bs[16 * 64];
  int bid = blockIdx.x;
  int t = threadIdx.x;
  if (bid < 256) {
    int bp = bid & 63, och = bid >> 6;
    int b = bp >> 2, p = bp & 3;
    int bt0 = b * 8 + 2 * p, bt1 = bt0 + 1;
    {
      float a0 = 0.f, a1 = 0.f;
      for (int q = 0; q < 4; ++q) {
        a0 += P[((size_t)q * 128 + bt0) * 256 + t];
        a1 += P[((size_t)q * 128 + bt1) * 256 + t];
      }
      float tb = thb[t];
      x0[t] = fmaxf(a0 + tb, 0.f);
      x1[t] = fmaxf(a1 + tb, 0.f);
    }
    __syncthreads();
    int o = och * 64 + (t & 63);
    int ks = t >> 6;
    const float* xa = (ks < 2) ? x0 : x1;
    const float* xb = (ks < 2) ? x1 : x0;
    int kbase = ks * 128;
    int xoff = (ks < 2) ? kbase : kbase - 256;
    float aa = 0.f, ab = 0.f;
#pragma unroll 8
    for (int ii = 0; ii < 128; ++ii) {
      float w = w1T[(size_t)(kbase + ii) * 256 + o];
      aa = fmaf(w, xa[xoff + ii], aa);
      ab = fmaf(w, xb[xoff + ii], ab);
    }
    ra[t] = aa;
    rb[t] = ab;
    __syncthreads();
    if (t < 64) {
      float sa = ra[t] + ra[64 + t] + ra[128 + t] + ra[192 + t];
      float sb = rb[t] + rb[64 + t] + rb[128 + t] + rb[192 + t];
      float bb = b1[o];
      h1[((size_t)bp * 2) * 256 + o] = fmaxf(sa + bb, 0.f);
      h1[((size_t)bp * 2 + 1) * 256 + o] = fmaxf(sb + bb, 0.f);
    }
    return;
  }
  int i = bid - 256;
  int n = i & 63, which = (i >> 6) & 1, th = (i >> 7) & 1;
  int b = n >> 2, p = n & 3;
  int tg = 2 * p + which;
  int tb = 2 * p + 1 - which;
  const f16* A = gammaFh + (size_t)(b * 8 + tg) * 32768;
  const f16* Bm = betaFh + (size_t)(b * 8 + tb) * 32768;
  float* out = (which ? Gs1 : Gs0) + (size_t)n * 16384;
  int ty = t >> 4, tx = t & 15;
  float acc[8][4] = {};
  for (int c0 = 0; c0 < 256; c0 += 16) {
    {
      int cc = t >> 4, col8 = (t & 15) * 8;
      f16x8 v = *(const f16x8*)(A + (size_t)(c0 + cc) * 128 + col8);
      for (int j = 0; j < 8; ++j) As[cc * 128 + col8 + j] = (float)v[j];
    }
    if (t < 128) {
      int cc = t >> 3, col8 = (t & 7) * 8;
      f16x8 v = *(const f16x8*)(Bm + (size_t)(c0 + cc) * 128 + th * 64 + col8);
      for (int j = 0; j < 8; ++j) Bs[cc * 64 + col8 + j] = (float)v[j];
    }
    __syncthreads();
    for (int cc = 0; cc < 16; ++cc) {
      float a8[8];
      *(float4*)a8 = *(const float4*)(As + cc * 128 + ty * 8);
      *(float4*)(a8 + 4) = *(const float4*)(As + cc * 128 + ty * 8 + 4);
      float4 b4 = *(const float4*)(Bs + cc * 64 + tx * 4);
      for (int ii = 0; ii < 8; ++ii) {
        acc[ii][0] = fmaf(a8[ii], b4.x, acc[ii][0]);
        acc[ii][1] = fmaf(a8[ii], b4.y, acc[ii][1]);
        acc[ii][2] = fmaf(a8[ii], b4.z, acc[ii][2]);
        acc[ii][3] = fmaf(a8[ii], b4.w, acc[ii][3]);
      }
    }
    __syncthreads();
  }
  for (int ii = 0; ii < 8; ++ii) {
    *(float4*)(out + (size_t)(ty * 8 + ii) * 128 + th * 64 + tx * 4) =
        make_float4(acc[ii][0], acc[ii][1], acc[ii][2], acc[ii][3]);
  }
}

// ---------------- Merged MlpB + Gj ----------------
__global__ __launch_bounds__(256) void kBG(const float* __restrict__ h1, const float* __restrict__ w2T,
                                           const float* __restrict__ b2,
                                           float* __restrict__ p00, float* __restrict__ p01,
                                           const float* __restrict__ Gs0, const float* __restrict__ Gs1,
                                           const float* __restrict__ ggT, const float* __restrict__ gg_b,
                                           const float* __restrict__ te_w, float* __restrict__ Sgj) {
  __shared__ float ha[256], hb[256];
  __shared__ float G0h[64 * 129];
  __shared__ __align__(16) float G1c[128 * 64];
  __shared__ float Red[16 * 64];
  int bid = blockIdx.x;
  int t = threadIdx.x;
  if (bid < 512) {
    int bp = bid & 63, chc = bid >> 6;
    ha[t] = h1[((size_t)bp * 2) * 256 + t];
    hb[t] = h1[((size_t)bp * 2 + 1) * 256 + t];
    __syncthreads();
    int ch = chc * 256 + t;
    float sa = 0.f, sb = 0.f;
#pragma unroll 8
    for (int k = 0; k < 256; ++k) {
      float w = w2T[(size_t)k * 2048 + ch];
      sa = fmaf(w, ha[k], sa);
      sb = fmaf(w, hb[k], sb);
    }
    p00[(size_t)bp * 2048 + ch] = sigmoidf_(sa + b2[ch]);
    p01[(size_t)bp * 2048 + ch] = sigmoidf_(sb + b2[ch]);
    return;
  }
  int i = bid - 512;
  int n = i & 63, gate = (i >> 6) & 1, hh = (i >> 7) & 1;
  const float* srcT = (gate == 0 ? Gs0 : Gs1) + (size_t)n * 16384;
  const float* srcC = (gate == 0 ? Gs1 : Gs0) + (size_t)n * 16384;
  for (int r = 0; r < 8; ++r) {
    int f = r * 256 + t;
    int hwl = f >> 5, c4 = (f & 31) * 4;
    float4 v = *(const float4*)(srcT + (size_t)(hh * 64 + hwl) * 128 + c4);
    G0h[hwl * 129 + c4 + 0] = v.x;
    G0h[hwl * 129 + c4 + 1] = v.y;
    G0h[hwl * 129 + c4 + 2] = v.z;
    G0h[hwl * 129 + c4 + 3] = v.w;
  }
  for (int r = 0; r < 8; ++r) {
    int f = r * 256 + t;
    int c = f >> 4, q = (f & 15) * 4;
    *(float4*)(G1c + c * 64 + q) = *(const float4*)(srcC + (size_t)c * 128 + hh * 64 + q);
  }
  __syncthreads();
  int ty = t >> 4, tx = t & 15;
  float acc[8][4] = {};
  for (int c = 0; c < 128; ++c) {
    float w8[8];
    *(float4*)w8 = *(const float4*)(ggT + (size_t)c * 128 + ty * 8);
    *(float4*)(w8 + 4) = *(const float4*)(ggT + (size_t)c * 128 + ty * 8 + 4);
    float g4[4];
    for (int j = 0; j < 4; ++j) g4[j] = G0h[(tx * 4 + j) * 129 + c];
    for (int ii = 0; ii < 8; ++ii)
      for (int j = 0; j < 4; ++j)
        acc[ii][j] = fmaf(w8[ii], g4[j], acc[ii][j]);
  }
  for (int c = 0; c < 128; ++c) {
    float w8[8];
    *(float4*)w8 = *(const float4*)(ggT + (size_t)(128 + c) * 128 + ty * 8);
    *(float4*)(w8 + 4) = *(const float4*)(ggT + (size_t)(128 + c) * 128 + ty * 8 + 4);
    float4 g = *(const float4*)(G1c + c * 64 + tx * 4);
    for (int ii = 0; ii < 8; ++ii) {
      acc[ii][0] = fmaf(w8[ii], g.x, acc[ii][0]);
      acc[ii][1] = fmaf(w8[ii], g.y, acc[ii][1]);
      acc[ii][2] = fmaf(w8[ii], g.z, acc[ii][2]);
      acc[ii][3] = fmaf(w8[ii], g.w, acc[ii][3]);
    }
  }
  float par[4] = {0.f, 0.f, 0.f, 0.f};
  for (int ii = 0; ii < 8; ++ii) {
    int o = ty * 8 + ii;
    float gb = gg_b[o], tw = te_w[128 + o];
    for (int j = 0; j < 4; ++j)
      par[j] += tw * fmaxf(acc[ii][j] + gb, 0.f);
  }
  for (int j = 0; j < 4; ++j) Red[ty * 64 + tx * 4 + j] = par[j];
  __syncthreads();
  if (t < 64) {
    float s = 0.f;
    for (int g = 0; g < 16; ++g) s += Red[g * 64 + t];
    Sgj[(size_t)gate * 8192 + n * 128 + hh * 64 + t] = s;
  }
}

// ---------------- final elementwise (gate sigmoid fused): out = relu(p00*pa*f0 + p01*pb*f1)^2 ----
__global__ __launch_bounds__(256) void kFinal(const float* __restrict__ featmap, const float* __restrict__ p00,
                                              const float* __restrict__ p01, const float* __restrict__ Sta,
                                              const float* __restrict__ Sgj, const float* __restrict__ te_s,
                                              const float* __restrict__ te_b, float* __restrict__ out) {
  int fid = blockIdx.x * 256 + threadIdx.x;
  int h4 = (fid & 31) * 4;
  int c = (fid >> 5) & 2047;
  int bp = fid >> 16;
  int b = bp >> 2, p = bp & 3;
  float ga = p00[(size_t)bp * 2048 + c];
  float gb = p01[(size_t)bp * 2048 + c];
  float ts = te_s[0], tbv = te_b[0];
  float4 sa0 = *(const float4*)(Sta + (size_t)bp * 128 + h4);
  float4 sg0 = *(const float4*)(Sgj + (size_t)bp * 128 + h4);
  float4 sa1 = *(const float4*)(Sta + 8192 + (size_t)bp * 128 + h4);
  float4 sg1 = *(const float4*)(Sgj + 8192 + (size_t)bp * 128 + h4);
  float4 pa4, pb4;
  pa4.x = sigmoidf_(ts * (sa0.x + sg0.x) + tbv);
  pa4.y = sigmoidf_(ts * (sa0.y + sg0.y) + tbv);
  pa4.z = sigmoidf_(ts * (sa0.z + sg0.z) + tbv);
  pa4.w = sigmoidf_(ts * (sa0.w + sg0.w) + tbv);
  pb4.x = sigmoidf_(ts * (sa1.x + sg1.x) + tbv);
  pb4.y = sigmoidf_(ts * (sa1.y + sg1.y) + tbv);
  pb4.z = sigmoidf_(ts * (sa1.z + sg1.z) + tbv);
  pb4.w = sigmoidf_(ts * (sa1.w + sg1.w) + tbv);
  const float* f0 = featmap + (size_t)(b * 8 + 2 * p) * 262144 + (size_t)c * 128 + h4;
  const float* f1 = f0 + 262144;
  float4 v0 = *(const float4*)f0;
  float4 v1 = *(const float4*)f1;
  float4 o4;
  float r;
  r = fmaxf(ga * pa4.x * v0.x + gb * pb4.x * v1.x, 0.f); o4.x = r * r;
  r = fmaxf(ga * pa4.y * v0.y + gb * pb4.y * v1.y, 0.f); o4.y = r * r;
  r = fmaxf(ga * pa4.z * v0.z + gb * pb4.z * v1.z, 0.f); o4.z = r * r;
  r = fmaxf(ga * pa4.w * v0.w + gb * pb4.w * v1.w, 0.f); o4.w = r * r;
  *(float4*)(out + (size_t)fid * 4) = o4;
}

extern "C" void kernel_launch(void* const* d_in, const int* in_sizes, int n_in,
                              void* d_out, int out_size, void* d_ws, size_t ws_size,
                              hipStream_t stream) {
  (void)in_sizes; (void)n_in; (void)out_size; (void)ws_size;
  const float* featmap    = (const float*)d_in[0];
  const float* re_featmap = (const float*)d_in[1];
  const float* vect       = (const float*)d_in[2];
  const float* embed      = (const float*)d_in[3];
  const float* gamma_w    = (const float*)d_in[4];
  const float* gamma_s    = (const float*)d_in[5];
  const float* gamma_b    = (const float*)d_in[6];
  const float* beta_w     = (const float*)d_in[7];
  const float* beta_s     = (const float*)d_in[8];
  const float* beta_b     = (const float*)d_in[9];
  const float* gg_w       = (const float*)d_in[10];
  const float* gg_s       = (const float*)d_in[11];
  const float* gg_b       = (const float*)d_in[12];
  const float* tte_w      = (const float*)d_in[13];
  const float* tte_s      = (const float*)d_in[14];
  const float* tte_b      = (const float*)d_in[15];
  const float* te_w       = (const float*)d_in[16];
  const float* te_s       = (const float*)d_in[17];
  const float* te_b       = (const float*)d_in[18];
  const float* theta_w    = (const float*)d_in[19];
  const float* theta_b    = (const float*)d_in[20];
  const float* cp_w1      = (const float*)d_in[21];
  const float* cp_b1      = (const float*)d_in[22];
  const float* cp_w2      = (const float*)d_in[23];
  const float* cp_b2      = (const float*)d_in[24];
  float* out = (float*)d_out;

  char* w = (char*)d_ws;
  f16* Wf  = (f16*)w;   w += (size_t)512 * 2048 * 2;
  f16* gammaFh = (f16*)w; w += (size_t)128 * 256 * 128 * 2;
  f16* betaFh  = (f16*)w; w += (size_t)128 * 256 * 128 * 2;
  float* Gs0    = (float*)w; w += (size_t)64 * 128 * 128 * 4;
  float* Gs1    = (float*)w; w += (size_t)64 * 128 * 128 * 4;
  float* ggT    = (float*)w; w += (size_t)256 * 128 * 4;
  float* tteT   = (float*)w; w += (size_t)256 * 128 * 4;
  float* thwT   = (float*)w; w += (size_t)2048 * 256 * 4;
  float* w1T    = (float*)w; w += (size_t)512 * 256 * 4;
  float* w2T    = (float*)w; w += (size_t)256 * 2048 * 4;
  float* P      = (float*)w; w += (size_t)4 * 128 * 256 * 4;
  float* h1     = (float*)w; w += (size_t)64 * 2 * 256 * 4;
  float* Sta    = (float*)w; w += (size_t)2 * 64 * 128 * 4;
  float* Sgj    = (float*)w; w += (size_t)2 * 64 * 128 * 4;
  float* p00    = (float*)w; w += (size_t)64 * 2048 * 4;
  float* p01    = (float*)w; w += (size_t)64 * 2048 * 4;

  kPP<<<816, 256, 0, stream>>>(gamma_w, gamma_s, beta_w, beta_s, gg_w, gg_s, tte_w, tte_s,
                               theta_w, cp_w1, cp_w2, Wf, ggT, tteT, thwT, w1T, w2T);
  kGemm8<<<256, 512, 0, stream>>>(re_featmap, Wf, gamma_b, beta_b, gammaFh, betaFh);
  kTT<<<768, 256, 0, stream>>>(vect, thwT, P, embed, tteT, tte_b, te_w, Sta);
  kAG<<<512, 256, 0, stream>>>(P, theta_b, w1T, cp_b1, h1, gammaFh, betaFh, Gs0, Gs1);
  kBG<<<768, 256, 0, stream>>>(h1, w2T, cp_b2, p00, p01, Gs0, Gs1, ggT, gg_b, te_w, Sgj);
  kFinal<<<16384, 256, 0, stream>>>(featmap, p00, p01, Sta, Sgj, te_s, te_b, out);
}

// Round 14
// 234.516 us; speedup vs baseline: 1.6777x; 1.0238x over previous
//
#include <hip/hip_runtime.h>
#include <stdint.h>

// Shapes: B=16 T=8 C=2048 H=16 W=8 -> C8=256 C4=512 HW=128 NP=4
// NIMG = B*T = 128, M = NIMG*HW = 16384, Ncat = 2*C8 = 512, K = 2048

typedef _Float16 f16;
typedef _Float16 f16x2 __attribute__((ext_vector_type(2)));
typedef _Float16 f16x4 __attribute__((ext_vector_type(4)));
typedef _Float16 f16x8 __attribute__((ext_vector_type(8)));
typedef float f32x4 __attribute__((ext_vector_type(4)));

typedef const void __attribute__((address_space(1)))* gptr1;
typedef void __attribute__((address_space(3)))* lptr3;

__device__ __forceinline__ void gload16(const void* g, void* l) {
  __builtin_amdgcn_global_load_lds((gptr1)g, (lptr3)l, 16, 0, 0);
}

__device__ __forceinline__ float sigmoidf_(float x) { return 1.f / (1.f + expf(-x)); }

#define WAIT_VM8 asm volatile("s_waitcnt vmcnt(8)" ::: "memory")
#define WAIT_VM0 asm volatile("s_waitcnt vmcnt(0)" ::: "memory")
#define WAIT_LGKM8 asm volatile("s_waitcnt lgkmcnt(8)" ::: "memory")
#define WAIT_LGKM0 asm volatile("s_waitcnt lgkmcnt(0)" ::: "memory")
#define SBAR __builtin_amdgcn_s_barrier()
#define SCHED0 __builtin_amdgcn_sched_barrier(0)

// ---------------- Prep: Wf f16 pre-swizzled + LDS-tiled weight transposes ----------------
__global__ __launch_bounds__(256) void kPP(const float* __restrict__ gw, const float* __restrict__ gs,
                                           const float* __restrict__ bw, const float* __restrict__ bs,
                                           const float* __restrict__ gg_w, const float* __restrict__ gg_s,
                                           const float* __restrict__ tte_w, const float* __restrict__ tte_s,
                                           const float* __restrict__ thw, const float* __restrict__ w1,
                                           const float* __restrict__ w2,
                                           f16* __restrict__ Wf,
                                           float* __restrict__ ggT, float* __restrict__ tteT,
                                           float* __restrict__ thwT, float* __restrict__ w1T,
                                           float* __restrict__ w2T) {
  __shared__ __align__(16) float TL[64][65];
  int t = threadIdx.x;
  int bid = blockIdx.x;
  if (bid < 512) {                   // Wf: 512 o * 256 chunks
    int id = bid * 256 + t;
    int o = id >> 8, cch = id & 255;
    float s; const float* row;
    if (o < 256) { s = gs[o]; row = gw + (size_t)o * 2048; }
    else         { s = bs[o - 256]; row = bw + (size_t)(o - 256) * 2048; }
    int kb = cch >> 3, sub = cch & 7;
    int subd = sub ^ (o & 7);
    f16x8 h8;
    for (int j = 0; j < 8; ++j)
      h8[j] = (f16)(row[cch * 8 + j] * s);
    size_t ob = (size_t)o * 2048 + (size_t)kb * 64 + (size_t)subd * 8;
    *(f16x8*)(Wf + ob) = h8;
    return;
  }
  int tb = bid - 512;
  const float* src; float* dst; const float* scale = nullptr; int R, C;
  if (tb < 128)      { src = thw;   dst = thwT; R = 256;  C = 2048; }
  else if (tb < 256) { tb -= 128; src = w2;  dst = w2T;  R = 2048; C = 256; }
  else if (tb < 288) { tb -= 256; src = w1;  dst = w1T;  R = 256;  C = 512; }
  else if (tb < 296) { tb -= 288; src = gg_w;  dst = ggT;  scale = gg_s;  R = 128; C = 256; }
  else               { tb -= 296; src = tte_w; dst = tteT; scale = tte_s; R = 128; C = 256; }
  int tpc = C >> 6;
  int r0 = (tb / tpc) * 64, c0 = (tb % tpc) * 64;
  int i16 = t >> 4, j4 = (t & 15) * 4;
  for (int s = 0; s < 4; ++s) {
    int i = i16 + s * 16;
    float4 v = *(const float4*)(src + (size_t)(r0 + i) * C + c0 + j4);
    TL[i][j4 + 0] = v.x; TL[i][j4 + 1] = v.y; TL[i][j4 + 2] = v.z; TL[i][j4 + 3] = v.w;
  }
  __syncthreads();
  for (int s = 0; s < 4; ++s) {
    int j = i16 + s * 16;
    float4 w;
    w.x = TL[j4 + 0][j]; w.y = TL[j4 + 1][j]; w.z = TL[j4 + 2][j]; w.w = TL[j4 + 3][j];
    if (scale) {
      w.x *= scale[r0 + j4 + 0]; w.y *= scale[r0 + j4 + 1];
      w.z *= scale[r0 + j4 + 2]; w.w *= scale[r0 + j4 + 3];
    }
    *(float4*)(dst + (size_t)(c0 + j) * R + r0 + j4) = w;
  }
}

// ---------------- Stage A GEMM with fused A-transpose (writes hidden under MFMA) ----------------
// C[16384][512] = A_f16 * Wf^T, A converted fp32->f16 in-kernel from re_featmap.
// Per step: barrier -> issue A(s+2)+W(s+2) -> 16 frag reads -> lgkm(8) -> MFMA_G(0)
//  || {vmcnt -> 8 ds_write A(s+1)} -> lgkm(8) -> MFMA_G(1) -> lgkm(0).
__global__ __launch_bounds__(512, 2) void kGemm8(const float* __restrict__ X, const f16* __restrict__ Wf,
                                                 const float* __restrict__ gamma_b, const float* __restrict__ beta_b,
                                                 f16* __restrict__ gammaFh, f16* __restrict__ betaFh) {
  __shared__ __align__(16) f16 S[3][24576];   // per buffer: A[0:8192], B[8192:24576] (f16 idx)
  int t = threadIdx.x;
  int lane = t & 63, wid = t >> 6;
  int wr = wid >> 2, wc = wid & 3;
  int bid = blockIdx.x;
  int bx = (bid & 7) * 16 + (bid >> 4);      // XCD pairing: by=0/1 share A on one XCD
  int by = (bid >> 3) & 1;
  size_t N0 = (size_t)by * 256;
  int row8 = wid * 8 + (lane >> 3);
  int sl = lane & 7;
  int fr = lane & 15, fq = lane >> 4;
  f32x4 acc[4][4] = {};
  f16x8 a[8], b[8];
  float4 ar0[4], ar1[4];                     // A staging register banks (parity)

  const float* Xb = X + (size_t)bx * 262144;
  int kkB = 2 * ((lane >> 3) + ((wid >> 2) << 3));   // even, 0..30
  int hw4 = ((lane & 7) << 2) + ((wid & 3) << 5);    // 0..124
  int wo[2][4];
#pragma unroll
  for (int r = 0; r < 2; ++r) {
    int kk = kkB + 32 * r;
    int cg = kk >> 3, kp = kk & 7;
#pragma unroll
    for (int j = 0; j < 4; ++j) {
      int hw = hw4 + j;
      wo[r][j] = hw * 64 + ((cg ^ (hw & 7)) << 3) + kp;
    }
  }

  const char* WB = (const char*)Wf;
  const size_t woff0 = (N0 + row8) * 4096 + (size_t)sl * 16;
  const size_t woff1 = (N0 + 64 + row8) * 4096 + (size_t)sl * 16;
  const size_t woff2 = (N0 + 128 + row8) * 4096 + (size_t)sl * 16;
  const size_t woff3 = (N0 + 192 + row8) * 4096 + (size_t)sl * 16;

#define AISSUE(bank, s) do {                                                       \
    const float* p_ = Xb + ((s) * 64 + kkB) * 128 + hw4;                           \
    bank[0] = *(const float4*)(p_);                                                \
    bank[1] = *(const float4*)(p_ + 128);                                          \
    bank[2] = *(const float4*)(p_ + 4096);                                         \
    bank[3] = *(const float4*)(p_ + 4096 + 128);                                   \
  } while (0)

#define WSTAGE(dst, s) do {                                                        \
    int koff_ = (s) << 7;                                                          \
    char* l_ = (char*)(dst) + 16384 + wid * 1024;                                  \
    gload16(WB + woff0 + koff_, l_);                                               \
    gload16(WB + woff1 + koff_, l_ + 8192);                                        \
    gload16(WB + woff2 + koff_, l_ + 16384);                                       \
    gload16(WB + woff3 + koff_, l_ + 24576);                                       \
  } while (0)

#define AWRITE(bank, dst) do {                                                     \
    f16* ad_ = (f16*)(dst);                                                        \
    _Pragma("unroll") for (int r_ = 0; r_ < 2; ++r_) {                             \
      const float* lo_ = (const float*)&bank[2 * r_];                              \
      const float* hi_ = (const float*)&bank[2 * r_ + 1];                          \
      _Pragma("unroll") for (int j_ = 0; j_ < 4; ++j_) {                           \
        f16x2 h_;                                                                  \
        h_[0] = (f16)lo_[j_];                                                      \
        h_[1] = (f16)hi_[j_];                                                      \
        *(f16x2*)(ad_ + wo[r_][j_]) = h_;                                          \
      }                                                                            \
    }                                                                              \
  } while (0)

#define LOADG(buf, g) do {                                                         \
    const f16* bA_ = (const f16*)(buf);                                            \
    const f16* bB_ = bA_ + 8192;                                                   \
    int cg_ = (g) * 4 + fq;                                                        \
    _Pragma("unroll") for (int mi = 0; mi < 4; ++mi) {                             \
      int m_ = wr * 64 + mi * 16 + fr;                                             \
      a[(g) * 4 + mi] = *(const f16x8*)(bA_ + m_ * 64 + ((cg_ ^ (m_ & 7)) << 3));  \
    }                                                                              \
    _Pragma("unroll") for (int ni = 0; ni < 4; ++ni) {                             \
      int n_ = wc * 64 + ni * 16 + fr;                                             \
      b[(g) * 4 + ni] = *(const f16x8*)(bB_ + n_ * 64 + ((cg_ ^ (n_ & 7)) << 3));  \
    }                                                                              \
  } while (0)

#define MFMA_G(g) do {                                                             \
    _Pragma("unroll") for (int mi = 0; mi < 4; ++mi)                               \
      _Pragma("unroll") for (int ni = 0; ni < 4; ++ni)                             \
        acc[mi][ni] = __builtin_amdgcn_mfma_f32_16x16x32_f16(                      \
            a[(g) * 4 + mi], b[(g) * 4 + ni], acc[mi][ni], 0, 0, 0);               \
  } while (0)

  // STEP s: cur=s%3, nxt=(s+1)%3, n2=(s+2)%3; issue bank = ar[s&1]; write bank = ar[(s+1)&1]
#define STEP(cur, nxt, n2, s, BI, BW) do {                                         \
    SBAR;                                                                          \
    if ((s) <= 29) { AISSUE(BI, (s) + 2); WSTAGE(n2, (s) + 2); }                   \
    SCHED0;                                                                        \
    LOADG(cur, 0);                                                                 \
    SCHED0;                                                                        \
    LOADG(cur, 1);                                                                 \
    WAIT_LGKM8;                                                                    \
    SCHED0;                                                                        \
    __builtin_amdgcn_s_setprio(1);                                                 \
    MFMA_G(0);                                                                     \
    if ((s) <= 30) {                                                               \
      if ((s) <= 29) { WAIT_VM8; } else { WAIT_VM0; }                              \
      SCHED0;                                                                      \
      AWRITE(BW, nxt);                                                             \
      WAIT_LGKM8;                                                                  \
      SCHED0;                                                                      \
      MFMA_G(1);                                                                   \
      __builtin_amdgcn_s_setprio(0);                                               \
      WAIT_LGKM0;                                                                  \
    } else {                                                                       \
      WAIT_LGKM0;                                                                  \
      SCHED0;                                                                      \
      MFMA_G(1);                                                                   \
      __builtin_amdgcn_s_setprio(0);                                               \
    }                                                                              \
  } while (0)

  // prologue: A(0)->ar0/buf0, A(1)->ar1/buf1
  AISSUE(ar0, 0); WSTAGE(&S[0][0], 0);
  SCHED0;
  AISSUE(ar1, 1); WSTAGE(&S[1][0], 1);
  SCHED0;
  WAIT_VM8;                 // A(0),W(0) done
  SCHED0;
  AWRITE(ar0, &S[0][0]);
  WAIT_LGKM0;

  for (int base = 0; base < 30; base += 6) {
    STEP(&S[0][0], &S[1][0], &S[2][0], base + 0, ar0, ar1);
    STEP(&S[1][0], &S[2][0], &S[0][0], base + 1, ar1, ar0);
    STEP(&S[2][0], &S[0][0], &S[1][0], base + 2, ar0, ar1);
    STEP(&S[0][0], &S[1][0], &S[2][0], base + 3, ar1, ar0);
    STEP(&S[1][0], &S[2][0], &S[0][0], base + 4, ar0, ar1);
    STEP(&S[2][0], &S[0][0], &S[1][0], base + 5, ar1, ar0);
  }
  STEP(&S[0][0], &S[1][0], &S[2][0], 30, ar0, ar1);   // writes A(31)->buf1, no issue
  STEP(&S[1][0], &S[2][0], &S[0][0], 31, ar1, ar0);   // reads buf1, no write
#undef STEP
#undef MFMA_G
#undef LOADG
#undef AWRITE
#undef WSTAGE
#undef AISSUE

  // epilogue: +bias, relu, store f16 to gammaFh/betaFh[n][o][hw]
  const float* bias = by ? beta_b : gamma_b;
  f16* outb = by ? betaFh : gammaFh;
#pragma unroll
  for (int mi = 0; mi < 4; ++mi) {
    int hwb = wr * 64 + mi * 16 + fq * 4;     // C/D: row = (lane>>4)*4 + reg
#pragma unroll
    for (int ni = 0; ni < 4; ++ni) {
      int o = wc * 64 + ni * 16 + fr;         // C/D: col = lane&15
      float bb = bias[o];
      f32x4 v = acc[mi][ni];
      f16x4 w;
      w[0] = (f16)fmaxf(v[0] + bb, 0.f);
      w[1] = (f16)fmaxf(v[1] + bb, 0.f);
      w[2] = (f16)fmaxf(v[2] + bb, 0.f);
      w[3] = (f16)fmaxf(v[3] + bb, 0.f);
      *(f16x4*)(outb + (size_t)bx * 32768 + (size_t)o * 128 + hwb) = w;
    }
  }
}

// ---------------- Merged Theta2 + Ta ----------------
__global__ __launch_bounds__(256) void kTT(const float* __restrict__ vect, const float* __restrict__ thwT,
                                           float* __restrict__ P,
                                           const float* __restrict__ embed, const float* __restrict__ tteT,
                                           const float* __restrict__ tte_b, const float* __restrict__ te_w,
                                           float* __restrict__ Sta) {
  __shared__ float V[512];
  __shared__ __align__(16) float E[256 * 64];
  __shared__ float Red[16 * 64];
  int bid = blockIdx.x;
  int t = threadIdx.x;
  if (bid < 512) {
    int bt = bid & 127, kq = bid >> 7;
    const float* src = vect + (size_t)bt * 2048 + kq * 512;
    if (t < 128) *(float4*)(V + t * 4) = *(const float4*)(src + t * 4);
    __syncthreads();
    const float* wp = thwT + (size_t)kq * 512 * 256 + t;
    float acc = 0.f;
#pragma unroll 8
    for (int c = 0; c < 512; ++c)
      acc = fmaf(wp[(size_t)c * 256], V[c], acc);
    P[((size_t)kq * 128 + bt) * 256 + t] = acc;
    return;
  }
  int i = bid - 512;
  int n = i & 63, gate = (i >> 6) & 1, hh = (i >> 7) & 1;
  int b = n >> 2, p = n & 3;
  const float* eA = embed + (size_t)(b * 8 + 2 * p + gate) * 16384 + hh * 64;
  const float* eB = embed + (size_t)(b * 8 + 2 * p + 1 - gate) * 16384 + hh * 64;
  for (int r = 0; r < 8; ++r) {
    int f = r * 256 + t;
    int ch = f >> 4, q = (f & 15) * 4;
    *(float4*)(E + ch * 64 + q) = *(const float4*)(eA + (size_t)ch * 128 + q);
  }
  for (int r = 0; r < 8; ++r) {
    int f = r * 256 + t;
    int ch = f >> 4, q = (f & 15) * 4;
    *(float4*)(E + (128 + ch) * 64 + q) = *(const float4*)(eB + (size_t)ch * 128 + q);
  }
  __syncthreads();
  int ty = t >> 4, tx = t & 15;
  float acc[8][4] = {};
  for (int c = 0; c < 256; ++c) {
    float w8[8];
    *(float4*)w8 = *(const float4*)(tteT + (size_t)c * 128 + ty * 8);
    *(float4*)(w8 + 4) = *(const float4*)(tteT + (size_t)c * 128 + ty * 8 + 4);
    float4 g = *(const float4*)(E + c * 64 + tx * 4);
    for (int ii = 0; ii < 8; ++ii) {
      acc[ii][0] = fmaf(w8[ii], g.x, acc[ii][0]);
      acc[ii][1] = fmaf(w8[ii], g.y, acc[ii][1]);
      acc[ii][2] = fmaf(w8[ii], g.z, acc[ii][2]);
      acc[ii][3] = fmaf(w8[ii], g.w, acc[ii][3]);
    }
  }
  float par[4] = {0.f, 0.f, 0.f, 0.f};
  for (int ii = 0; ii < 8; ++ii) {
    int o = ty * 8 + ii;
    float tb = tte_b[o], tw = te_w[o];
    for (int j = 0; j < 4; ++j)
      par[j] += tw * fmaxf(acc[ii][j] + tb, 0.f);
  }
  for (int j = 0; j < 4; ++j) Red[ty * 64 + tx * 4 + j] = par[j];
  __syncthreads();
  if (t < 64) {
    float s = 0.f;
    for (int g = 0; g < 16; ++g) s += Red[g * 64 + t];
    Sta[(size_t)gate * 8192 + n * 128 + hh * 64 + t] = s;
  }
}

// ---------------- Merged MlpA + Gs (gammaF/betaF are f16) ----------------
__global__ __launch_bounds__(256) void kAG(const float* __restrict__ P, const float* __restrict__ thb,
                                           const float* __restrict__ w1T, const float* __restrict__ b1,
                                           float* __restrict__ h1,
                                           const f16* __restrict__ gammaFh, const f16* __restrict__ betaFh,
                                           float* __restrict__ Gs0, float* __restrict__ Gs1) {
  __shared__ float x0[256], x1[256];
  __shared__ float ra[256], rb[256];
  __shared__ __align__(16) float As[16 * 128];
  __shared__ __align__(16) float Bs[16 * 64];
  int bid = blockIdx.x;
  int t = threadIdx.x;
  if (bid < 256) {
    int bp = bid & 63, och = bid >> 6;
    int b = bp >> 2, p = bp & 3;
    int bt0 = b * 8 + 2 * p, bt1 = bt0 + 1;
    {
      float a0 = 0.f, a1 = 0.f;
      for (int q = 0; q < 4; ++q) {
        a0 += P[((size_t)q * 128 + bt0) * 256 + t];
        a1 += P[((size_t)q * 128 + bt1) * 256 + t];
      }
      float tb = thb[t];
      x0[t] = fmaxf(a0 + tb, 0.f);
      x1[t] = fmaxf(a1 + tb, 0.f);
    }
    __syncthreads();
    int o = och * 64 + (t & 63);
    int ks = t >> 6;
    const float* xa = (ks < 2) ? x0 : x1;
    const float* xb = (ks < 2) ? x1 : x0;
    int kbase = ks * 128;
    int xoff = (ks < 2) ? kbase : kbase - 256;
    float aa = 0.f, ab = 0.f;
#pragma unroll 8
    for (int ii = 0; ii < 128; ++ii) {
      float w = w1T[(size_t)(kbase + ii) * 256 + o];
      aa = fmaf(w, xa[xoff + ii], aa);
      ab = fmaf(w, xb[xoff + ii], ab);
    }
    ra[t] = aa;
    rb[t] = ab;
    __syncthreads();
    if (t < 64) {
      float sa = ra[t] + ra[64 + t] + ra[128 + t] + ra[192 + t];
      float sb = rb[t] + rb[64 + t] + rb[128 + t] + rb[192 + t];
      float bb = b1[o];
      h1[((size_t)bp * 2) * 256 + o] = fmaxf(sa + bb, 0.f);
      h1[((size_t)bp * 2 + 1) * 256 + o] = fmaxf(sb + bb, 0.f);
    }
    return;
  }
  int i = bid - 256;
  int n = i & 63, which = (i >> 6) & 1, th = (i >> 7) & 1;
  int b = n >> 2, p = n & 3;
  int tg = 2 * p + which;
  int tb = 2 * p + 1 - which;
  const f16* A = gammaFh + (size_t)(b * 8 + tg) * 32768;
  const f16* Bm = betaFh + (size_t)(b * 8 + tb) * 32768;
  float* out = (which ? Gs1 : Gs0) + (size_t)n * 16384;
  int ty = t >> 4, tx = t & 15;
  float acc[8][4] = {};
  for (int c0 = 0; c0 < 256; c0 += 16) {
    {
      int cc = t >> 4, col8 = (t & 15) * 8;
      f16x8 v = *(const f16x8*)(A + (size_t)(c0 + cc) * 128 + col8);
      for (int j = 0; j < 8; ++j) As[cc * 128 + col8 + j] = (float)v[j];
    }
    if (t < 128) {
      int cc = t >> 3, col8 = (t & 7) * 8;
      f16x8 v = *(const f16x8*)(Bm + (size_t)(c0 + cc) * 128 + th * 64 + col8);
      for (int j = 0; j < 8; ++j) Bs[cc * 64 + col8 + j] = (float)v[j];
    }
    __syncthreads();
    for (int cc = 0; cc < 16; ++cc) {
      float a8[8];
      *(float4*)a8 = *(const float4*)(As + cc * 128 + ty * 8);
      *(float4*)(a8 + 4) = *(const float4*)(As + cc * 128 + ty * 8 + 4);
      float4 b4 = *(const float4*)(Bs + cc * 64 + tx * 4);
      for (int ii = 0; ii < 8; ++ii) {
        acc[ii][0] = fmaf(a8[ii], b4.x, acc[ii][0]);
        acc[ii][1] = fmaf(a8[ii], b4.y, acc[ii][1]);
        acc[ii][2] = fmaf(a8[ii], b4.z, acc[ii][2]);
        acc[ii][3] = fmaf(a8[ii], b4.w, acc[ii][3]);
      }
    }
    __syncthreads();
  }
  for (int ii = 0; ii < 8; ++ii) {
    *(float4*)(out + (size_t)(ty * 8 + ii) * 128 + th * 64 + tx * 4) =
        make_float4(acc[ii][0], acc[ii][1], acc[ii][2], acc[ii][3]);
  }
}

// ---------------- Merged MlpB + Gj ----------------
__global__ __launch_bounds__(256) void kBG(const float* __restrict__ h1, const float* __restrict__ w2T,
                                           const float* __restrict__ b2,
                                           float* __restrict__ p00, float* __restrict__ p01,
                                           const float* __restrict__ Gs0, const float* __restrict__ Gs1,
                                           const float* __restrict__ ggT, const float* __restrict__ gg_b,
                                           const float* __restrict__ te_w, float* __restrict__ Sgj) {
  __shared__ float ha[256], hb[256];
  __shared__ float G0h[64 * 129];
  __shared__ __align__(16) float G1c[128 * 64];
  __shared__ float Red[16 * 64];
  int bid = blockIdx.x;
  int t = threadIdx.x;
  if (bid < 512) {
    int bp = bid & 63, chc = bid >> 6;
    ha[t] = h1[((size_t)bp * 2) * 256 + t];
    hb[t] = h1[((size_t)bp * 2 + 1) * 256 + t];
    __syncthreads();
    int ch = chc * 256 + t;
    float sa = 0.f, sb = 0.f;
#pragma unroll 8
    for (int k = 0; k < 256; ++k) {
      float w = w2T[(size_t)k * 2048 + ch];
      sa = fmaf(w, ha[k], sa);
      sb = fmaf(w, hb[k], sb);
    }
    p00[(size_t)bp * 2048 + ch] = sigmoidf_(sa + b2[ch]);
    p01[(size_t)bp * 2048 + ch] = sigmoidf_(sb + b2[ch]);
    return;
  }
  int i = bid - 512;
  int n = i & 63, gate = (i >> 6) & 1, hh = (i >> 7) & 1;
  const float* srcT = (gate == 0 ? Gs0 : Gs1) + (size_t)n * 16384;
  const float* srcC = (gate == 0 ? Gs1 : Gs0) + (size_t)n * 16384;
  for (int r = 0; r < 8; ++r) {
    int f = r * 256 + t;
    int hwl = f >> 5, c4 = (f & 31) * 4;
    float4 v = *(const float4*)(srcT + (size_t)(hh * 64 + hwl) * 128 + c4);
    G0h[hwl * 129 + c4 + 0] = v.x;
    G0h[hwl * 129 + c4 + 1] = v.y;
    G0h[hwl * 129 + c4 + 2] = v.z;
    G0h[hwl * 129 + c4 + 3] = v.w;
  }
  for (int r = 0; r < 8; ++r) {
    int f = r * 256 + t;
    int c = f >> 4, q = (f & 15) * 4;
    *(float4*)(G1c + c * 64 + q) = *(const float4*)(srcC + (size_t)c * 128 + hh * 64 + q);
  }
  __syncthreads();
  int ty = t >> 4, tx = t & 15;
  float acc[8][4] = {};
  for (int c = 0; c < 128; ++c) {
    float w8[8];
    *(float4*)w8 = *(const float4*)(ggT + (size_t)c * 128 + ty * 8);
    *(float4*)(w8 + 4) = *(const float4*)(ggT + (size_t)c * 128 + ty * 8 + 4);
    float g4[4];
    for (int j = 0; j < 4; ++j) g4[j] = G0h[(tx * 4 + j) * 129 + c];
    for (int ii = 0; ii < 8; ++ii)
      for (int j = 0; j < 4; ++j)
        acc[ii][j] = fmaf(w8[ii], g4[j], acc[ii][j]);
  }
  for (int c = 0; c < 128; ++c) {
    float w8[8];
    *(float4*)w8 = *(const float4*)(ggT + (size_t)(128 + c) * 128 + ty * 8);
    *(float4*)(w8 + 4) = *(const float4*)(ggT + (size_t)(128 + c) * 128 + ty * 8 + 4);
    float4 g = *(const float4*)(G1c + c * 64 + tx * 4);
    for (int ii = 0; ii < 8; ++ii) {
      acc[ii][0] = fmaf(w8[ii], g.x, acc[ii][0]);
      acc[ii][1] = fmaf(w8[ii], g.y, acc[ii][1]);
      acc[ii][2] = fmaf(w8[ii], g.z, acc[ii][2]);
      acc[ii][3] = fmaf(w8[ii], g.w, acc[ii][3]);
    }
  }
  float par[4] = {0.f, 0.f, 0.f, 0.f};
  for (int ii = 0; ii < 8; ++ii) {
    int o = ty * 8 + ii;
    float gb = gg_b[o], tw = te_w[128 + o];
    for (int j = 0; j < 4; ++j)
      par[j] += tw * fmaxf(acc[ii][j] + gb, 0.f);
  }
  for (int j = 0; j < 4; ++j) Red[ty * 64 + tx * 4 + j] = par[j];
  __syncthreads();
  if (t < 64) {
    float s = 0.f;
    for (int g = 0; g < 16; ++g) s += Red[g * 64 + t];
    Sgj[(size_t)gate * 8192 + n * 128 + hh * 64 + t] = s;
  }
}

// ---------------- final elementwise (gate sigmoid fused): out = relu(p00*pa*f0 + p01*pb*f1)^2 ----
__global__ __launch_bounds__(256) void kFinal(const float* __restrict__ featmap, const float* __restrict__ p00,
                                              const float* __restrict__ p01, const float* __restrict__ Sta,
                                              const float* __restrict__ Sgj, const float* __restrict__ te_s,
                                              const float* __restrict__ te_b, float* __restrict__ out) {
  int fid = blockIdx.x * 256 + threadIdx.x;
  int h4 = (fid & 31) * 4;
  int c = (fid >> 5) & 2047;
  int bp = fid >> 16;
  int b = bp >> 2, p = bp & 3;
  float ga = p00[(size_t)bp * 2048 + c];
  float gb = p01[(size_t)bp * 2048 + c];
  float ts = te_s[0], tbv = te_b[0];
  float4 sa0 = *(const float4*)(Sta + (size_t)bp * 128 + h4);
  float4 sg0 = *(const float4*)(Sgj + (size_t)bp * 128 + h4);
  float4 sa1 = *(const float4*)(Sta + 8192 + (size_t)bp * 128 + h4);
  float4 sg1 = *(const float4*)(Sgj + 8192 + (size_t)bp * 128 + h4);
  float4 pa4, pb4;
  pa4.x = sigmoidf_(ts * (sa0.x + sg0.x) + tbv);
  pa4.y = sigmoidf_(ts * (sa0.y + sg0.y) + tbv);
  pa4.z = sigmoidf_(ts * (sa0.z + sg0.z) + tbv);
  pa4.w = sigmoidf_(ts * (sa0.w + sg0.w) + tbv);
  pb4.x = sigmoidf_(ts * (sa1.x + sg1.x) + tbv);
  pb4.y = sigmoidf_(ts * (sa1.y + sg1.y) + tbv);
  pb4.z = sigmoidf_(ts * (sa1.z + sg1.z) + tbv);
  pb4.w = sigmoidf_(ts * (sa1.w + sg1.w) + tbv);
  const float* f0 = featmap + (size_t)(b * 8 + 2 * p) * 262144 + (size_t)c * 128 + h4;
  const float* f1 = f0 + 262144;
  float4 v0 = *(const float4*)f0;
  float4 v1 = *(const float4*)f1;
  float4 o4;
  float r;
  r = fmaxf(ga * pa4.x * v0.x + gb * pb4.x * v1.x, 0.f); o4.x = r * r;
  r = fmaxf(ga * pa4.y * v0.y + gb * pb4.y * v1.y, 0.f); o4.y = r * r;
  r = fmaxf(ga * pa4.z * v0.z + gb * pb4.z * v1.z, 0.f); o4.z = r * r;
  r = fmaxf(ga * pa4.w * v0.w + gb * pb4.w * v1.w, 0.f); o4.w = r * r;
  *(float4*)(out + (size_t)fid * 4) = o4;
}

extern "C" void kernel_launch(void* const* d_in, const int* in_sizes, int n_in,
                              void* d_out, int out_size, void* d_ws, size_t ws_size,
                              hipStream_t stream) {
  (void)in_sizes; (void)n_in; (void)out_size; (void)ws_size;
  const float* featmap    = (const float*)d_in[0];
  const float* re_featmap = (const float*)d_in[1];
  const float* vect       = (const float*)d_in[2];
  const float* embed      = (const float*)d_in[3];
  const float* gamma_w    = (const float*)d_in[4];
  const float* gamma_s    = (const float*)d_in[5];
  const float* gamma_b    = (const float*)d_in[6];
  const float* beta_w     = (const float*)d_in[7];
  const float* beta_s     = (const float*)d_in[8];
  const float* beta_b     = (const float*)d_in[9];
  const float* gg_w       = (const float*)d_in[10];
  const float* gg_s       = (const float*)d_in[11];
  const float* gg_b       = (const float*)d_in[12];
  const float* tte_w      = (const float*)d_in[13];
  const float* tte_s      = (const float*)d_in[14];
  const float* tte_b      = (const float*)d_in[15];
  const float* te_w       = (const float*)d_in[16];
  const float* te_s       = (const float*)d_in[17];
  const float* te_b       = (const float*)d_in[18];
  const float* theta_w    = (const float*)d_in[19];
  const float* theta_b    = (const float*)d_in[20];
  const float* cp_w1      = (const float*)d_in[21];
  const float* cp_b1      = (const float*)d_in[22];
  const float* cp_w2      = (const float*)d_in[23];
  const float* cp_b2      = (const float*)d_in[24];
  float* out = (float*)d_out;

  char* w = (char*)d_ws;
  f16* Wf  = (f16*)w;   w += (size_t)512 * 2048 * 2;
  f16* gammaFh = (f16*)w; w += (size_t)128 * 256 * 128 * 2;
  f16* betaFh  = (f16*)w; w += (size_t)128 * 256 * 128 * 2;
  float* Gs0    = (float*)w; w += (size_t)64 * 128 * 128 * 4;
  float* Gs1    = (float*)w; w += (size_t)64 * 128 * 128 * 4;
  float* ggT    = (float*)w; w += (size_t)256 * 128 * 4;
  float* tteT   = (float*)w; w += (size_t)256 * 128 * 4;
  float* thwT   = (float*)w; w += (size_t)2048 * 256 * 4;
  float* w1T    = (float*)w; w += (size_t)512 * 256 * 4;
  float* w2T    = (float*)w; w += (size_t)256 * 2048 * 4;
  float* P      = (float*)w; w += (size_t)4 * 128 * 256 * 4;
  float* h1     = (float*)w; w += (size_t)64 * 2 * 256 * 4;
  float* Sta    = (float*)w; w += (size_t)2 * 64 * 128 * 4;
  float* Sgj    = (float*)w; w += (size_t)2 * 64 * 128 * 4;
  float* p00    = (float*)w; w += (size_t)64 * 2048 * 4;
  float* p01    = (float*)w; w += (size_t)64 * 2048 * 4;

  kPP<<<816, 256, 0, stream>>>(gamma_w, gamma_s, beta_w, beta_s, gg_w, gg_s, tte_w, tte_s,
                               theta_w, cp_w1, cp_w2, Wf, ggT, tteT, thwT, w1T, w2T);
  kGemm8<<<256, 512, 0, stream>>>(re_featmap, Wf, gamma_b, beta_b, gammaFh, betaFh);
  kTT<<<768, 256, 0, stream>>>(vect, thwT, P, embed, tteT, tte_b, te_w, Sta);
  kAG<<<512, 256, 0, stream>>>(P, theta_b, w1T, cp_b1, h1, gammaFh, betaFh, Gs0, Gs1);
  kBG<<<768, 256, 0, stream>>>(h1, w2T, cp_b2, p00, p01, Gs0, Gs1, ggT, gg_b, te_w, Sgj);
  kFinal<<<16384, 256, 0, stream>>>(featmap, p00, p01, Sta, Sgj, te_s, te_b, out);
}

// Round 15
// 234.143 us; speedup vs baseline: 1.6804x; 1.0016x over previous
//
#include <hip/hip_runtime.h>
#include <stdint.h>

// Shapes: B=16 T=8 C=2048 H=16 W=8 -> C8=256 C4=512 HW=128 NP=4
// NIMG = B*T = 128, M = NIMG*HW = 16384, Ncat = 2*C8 = 512, K = 2048

typedef _Float16 f16;
typedef _Float16 f16x2 __attribute__((ext_vector_type(2)));
typedef _Float16 f16x4 __attribute__((ext_vector_type(4)));
typedef _Float16 f16x8 __attribute__((ext_vector_type(8)));
typedef float f32x4 __attribute__((ext_vector_type(4)));

typedef const void __attribute__((address_space(1)))* gptr1;
typedef void __attribute__((address_space(3)))* lptr3;

__device__ __forceinline__ void gload16(const void* g, void* l) {
  __builtin_amdgcn_global_load_lds((gptr1)g, (lptr3)l, 16, 0, 0);
}

__device__ __forceinline__ float sigmoidf_(float x) { return 1.f / (1.f + expf(-x)); }

#define WAIT_VM20 asm volatile("s_waitcnt vmcnt(20)" ::: "memory")
#define WAIT_VM0 asm volatile("s_waitcnt vmcnt(0)" ::: "memory")
#define WAIT_LGKM8 asm volatile("s_waitcnt lgkmcnt(8)" ::: "memory")
#define WAIT_LGKM0 asm volatile("s_waitcnt lgkmcnt(0)" ::: "memory")
#define SBAR __builtin_amdgcn_s_barrier()
#define SCHED0 __builtin_amdgcn_sched_barrier(0)

// ---------------- Prep: Wf f16 pre-swizzled + LDS-tiled weight transposes ----------------
__global__ __launch_bounds__(256) void kPP(const float* __restrict__ gw, const float* __restrict__ gs,
                                           const float* __restrict__ bw, const float* __restrict__ bs,
                                           const float* __restrict__ gg_w, const float* __restrict__ gg_s,
                                           const float* __restrict__ tte_w, const float* __restrict__ tte_s,
                                           const float* __restrict__ thw, const float* __restrict__ w1,
                                           const float* __restrict__ w2,
                                           f16* __restrict__ Wf,
                                           float* __restrict__ ggT, float* __restrict__ tteT,
                                           float* __restrict__ thwT, float* __restrict__ w1T,
                                           float* __restrict__ w2T) {
  __shared__ __align__(16) float TL[64][65];
  int t = threadIdx.x;
  int bid = blockIdx.x;
  if (bid < 512) {                   // Wf: 512 o * 256 chunks
    int id = bid * 256 + t;
    int o = id >> 8, cch = id & 255;
    float s; const float* row;
    if (o < 256) { s = gs[o]; row = gw + (size_t)o * 2048; }
    else         { s = bs[o - 256]; row = bw + (size_t)(o - 256) * 2048; }
    int kb = cch >> 3, sub = cch & 7;
    int subd = sub ^ (o & 7);
    f16x8 h8;
    for (int j = 0; j < 8; ++j)
      h8[j] = (f16)(row[cch * 8 + j] * s);
    size_t ob = (size_t)o * 2048 + (size_t)kb * 64 + (size_t)subd * 8;
    *(f16x8*)(Wf + ob) = h8;
    return;
  }
  int tb = bid - 512;
  const float* src; float* dst; const float* scale = nullptr; int R, C;
  if (tb < 128)      { src = thw;   dst = thwT; R = 256;  C = 2048; }
  else if (tb < 256) { tb -= 128; src = w2;  dst = w2T;  R = 2048; C = 256; }
  else if (tb < 288) { tb -= 256; src = w1;  dst = w1T;  R = 256;  C = 512; }
  else if (tb < 296) { tb -= 288; src = gg_w;  dst = ggT;  scale = gg_s;  R = 128; C = 256; }
  else               { tb -= 296; src = tte_w; dst = tteT; scale = tte_s; R = 128; C = 256; }
  int tpc = C >> 6;
  int r0 = (tb / tpc) * 64, c0 = (tb % tpc) * 64;
  int i16 = t >> 4, j4 = (t & 15) * 4;
  for (int s = 0; s < 4; ++s) {
    int i = i16 + s * 16;
    float4 v = *(const float4*)(src + (size_t)(r0 + i) * C + c0 + j4);
    TL[i][j4 + 0] = v.x; TL[i][j4 + 1] = v.y; TL[i][j4 + 2] = v.z; TL[i][j4 + 3] = v.w;
  }
  __syncthreads();
  for (int s = 0; s < 4; ++s) {
    int j = i16 + s * 16;
    float4 w;
    w.x = TL[j4 + 0][j]; w.y = TL[j4 + 1][j]; w.z = TL[j4 + 2][j]; w.w = TL[j4 + 3][j];
    if (scale) {
      w.x *= scale[r0 + j4 + 0]; w.y *= scale[r0 + j4 + 1];
      w.z *= scale[r0 + j4 + 2]; w.w *= scale[r0 + j4 + 3];
    }
    *(float4*)(dst + (size_t)(c0 + j) * R + r0 + j4) = w;
  }
}

// ---------------- Stage A GEMM with fused A-transpose (k-contiguous staging, b128 writes) ----------------
// C[16384][512] = A_f16 * Wf^T, A converted fp32->f16 in-kernel from re_featmap.
// Per thread A-stage: 1 hw x 16 k -> 16 coalesced dword loads, 2 ds_write_b128 (conflict-free).
// Per step: barrier -> issue A(s+2)[16]+W(s+2)[4] -> 16 frag reads -> lgkm(8) -> MFMA_G(0)
//  || {vmcnt(20|0) -> 2 ds_write_b128 A(s+1)} -> lgkm(8) -> MFMA_G(1) -> lgkm(0).
__global__ __launch_bounds__(512, 2) void kGemm8(const float* __restrict__ X, const f16* __restrict__ Wf,
                                                 const float* __restrict__ gamma_b, const float* __restrict__ beta_b,
                                                 f16* __restrict__ gammaFh, f16* __restrict__ betaFh) {
  __shared__ __align__(16) f16 S[3][24576];   // per buffer: A[0:8192], B[8192:24576] (f16 idx)
  int t = threadIdx.x;
  int lane = t & 63, wid = t >> 6;
  int wr = wid >> 2, wc = wid & 3;
  int bid = blockIdx.x;
  int bx = (bid & 7) * 16 + (bid >> 4);      // XCD pairing: by=0/1 share A on one XCD
  int by = (bid >> 3) & 1;
  size_t N0 = (size_t)by * 256;
  int row8 = wid * 8 + (lane >> 3);
  int sl = lane & 7;
  int fr = lane & 15, fq = lane >> 4;
  f32x4 acc[4][4] = {};
  f16x8 a[8], b[8];
  float ar0[16], ar1[16];                    // A staging register banks (parity)

  const float* Xb = X + (size_t)bx * 262144;
  int hwl = lane + (wid & 1) * 64;           // 0..127
  int kg = wid >> 1;                         // 0..3 (16 k each)
  int kg16 = kg * 16;
  int woA[2];
#pragma unroll
  for (int r = 0; r < 2; ++r) {
    int cg = kg * 2 + r;                     // 8-f16 chunk index (k = cg*8..+7)
    woA[r] = hwl * 64 + ((cg ^ (hwl & 7)) << 3);
  }

  const char* WB = (const char*)Wf;
  const size_t woff0 = (N0 + row8) * 4096 + (size_t)sl * 16;
  const size_t woff1 = (N0 + 64 + row8) * 4096 + (size_t)sl * 16;
  const size_t woff2 = (N0 + 128 + row8) * 4096 + (size_t)sl * 16;
  const size_t woff3 = (N0 + 192 + row8) * 4096 + (size_t)sl * 16;

#define AISSUE(bank, s) do {                                                       \
    const float* p_ = Xb + ((s) * 64 + kg16) * 128 + hwl;                          \
    _Pragma("unroll") for (int j_ = 0; j_ < 16; ++j_)                              \
      bank[j_] = p_[j_ * 128];                                                     \
  } while (0)

#define WSTAGE(dst, s) do {                                                        \
    int koff_ = (s) << 7;                                                          \
    char* l_ = (char*)(dst) + 16384 + wid * 1024;                                  \
    gload16(WB + woff0 + koff_, l_);                                               \
    gload16(WB + woff1 + koff_, l_ + 8192);                                        \
    gload16(WB + woff2 + koff_, l_ + 16384);                                       \
    gload16(WB + woff3 + koff_, l_ + 24576);                                       \
  } while (0)

#define AWRITE(bank, dst) do {                                                     \
    f16* ad_ = (f16*)(dst);                                                        \
    _Pragma("unroll") for (int r_ = 0; r_ < 2; ++r_) {                             \
      f16x8 h_;                                                                    \
      _Pragma("unroll") for (int i_ = 0; i_ < 8; ++i_)                             \
        h_[i_] = (f16)bank[r_ * 8 + i_];                                           \
      *(f16x8*)(ad_ + woA[r_]) = h_;                                               \
    }                                                                              \
  } while (0)

#define LOADG(buf, g) do {                                                         \
    const f16* bA_ = (const f16*)(buf);                                            \
    const f16* bB_ = bA_ + 8192;                                                   \
    int cg_ = (g) * 4 + fq;                                                        \
    _Pragma("unroll") for (int mi = 0; mi < 4; ++mi) {                             \
      int m_ = wr * 64 + mi * 16 + fr;                                             \
      a[(g) * 4 + mi] = *(const f16x8*)(bA_ + m_ * 64 + ((cg_ ^ (m_ & 7)) << 3));  \
    }                                                                              \
    _Pragma("unroll") for (int ni = 0; ni < 4; ++ni) {                             \
      int n_ = wc * 64 + ni * 16 + fr;                                             \
      b[(g) * 4 + ni] = *(const f16x8*)(bB_ + n_ * 64 + ((cg_ ^ (n_ & 7)) << 3));  \
    }                                                                              \
  } while (0)

#define MFMA_G(g) do {                                                             \
    _Pragma("unroll") for (int mi = 0; mi < 4; ++mi)                               \
      _Pragma("unroll") for (int ni = 0; ni < 4; ++ni)                             \
        acc[mi][ni] = __builtin_amdgcn_mfma_f32_16x16x32_f16(                      \
            a[(g) * 4 + mi], b[(g) * 4 + ni], acc[mi][ni], 0, 0, 0);               \
  } while (0)

  // STEP s: cur=s%3, nxt=(s+1)%3, n2=(s+2)%3; issue bank = ar[s&1]; write bank = ar[(s+1)&1]
#define STEP(cur, nxt, n2, s, BI, BW) do {                                         \
    SBAR;                                                                          \
    if ((s) <= 29) { AISSUE(BI, (s) + 2); WSTAGE(n2, (s) + 2); }                   \
    SCHED0;                                                                        \
    LOADG(cur, 0);                                                                 \
    SCHED0;                                                                        \
    LOADG(cur, 1);                                                                 \
    WAIT_LGKM8;                                                                    \
    SCHED0;                                                                        \
    __builtin_amdgcn_s_setprio(1);                                                 \
    MFMA_G(0);                                                                     \
    if ((s) <= 30) {                                                               \
      if ((s) <= 29) { WAIT_VM20; } else { WAIT_VM0; }                             \
      SCHED0;                                                                      \
      AWRITE(BW, nxt);                                                             \
      WAIT_LGKM8;                                                                  \
      SCHED0;                                                                      \
      MFMA_G(1);                                                                   \
      __builtin_amdgcn_s_setprio(0);                                               \
      WAIT_LGKM0;                                                                  \
    } else {                                                                       \
      WAIT_LGKM0;                                                                  \
      SCHED0;                                                                      \
      MFMA_G(1);                                                                   \
      __builtin_amdgcn_s_setprio(0);                                               \
    }                                                                              \
  } while (0)

  // prologue: A(0)->ar0/buf0, A(1)->ar1/buf1
  AISSUE(ar0, 0); WSTAGE(&S[0][0], 0);
  SCHED0;
  AISSUE(ar1, 1); WSTAGE(&S[1][0], 1);
  SCHED0;
  WAIT_VM20;                // A(0),W(0) done
  SCHED0;
  AWRITE(ar0, &S[0][0]);
  WAIT_LGKM0;

  for (int base = 0; base < 30; base += 6) {
    STEP(&S[0][0], &S[1][0], &S[2][0], base + 0, ar0, ar1);
    STEP(&S[1][0], &S[2][0], &S[0][0], base + 1, ar1, ar0);
    STEP(&S[2][0], &S[0][0], &S[1][0], base + 2, ar0, ar1);
    STEP(&S[0][0], &S[1][0], &S[2][0], base + 3, ar1, ar0);
    STEP(&S[1][0], &S[2][0], &S[0][0], base + 4, ar0, ar1);
    STEP(&S[2][0], &S[0][0], &S[1][0], base + 5, ar1, ar0);
  }
  STEP(&S[0][0], &S[1][0], &S[2][0], 30, ar0, ar1);   // writes A(31)->buf1, no issue
  STEP(&S[1][0], &S[2][0], &S[0][0], 31, ar1, ar0);   // reads buf1, no write
#undef STEP
#undef MFMA_G
#undef LOADG
#undef AWRITE
#undef WSTAGE
#undef AISSUE

  // epilogue: +bias, relu, store f16 to gammaFh/betaFh[n][o][hw]
  const float* bias = by ? beta_b : gamma_b;
  f16* outb = by ? betaFh : gammaFh;
#pragma unroll
  for (int mi = 0; mi < 4; ++mi) {
    int hwb = wr * 64 + mi * 16 + fq * 4;     // C/D: row = (lane>>4)*4 + reg
#pragma unroll
    for (int ni = 0; ni < 4; ++ni) {
      int o = wc * 64 + ni * 16 + fr;         // C/D: col = lane&15
      float bb = bias[o];
      f32x4 v = acc[mi][ni];
      f16x4 w;
      w[0] = (f16)fmaxf(v[0] + bb, 0.f);
      w[1] = (f16)fmaxf(v[1] + bb, 0.f);
      w[2] = (f16)fmaxf(v[2] + bb, 0.f);
      w[3] = (f16)fmaxf(v[3] + bb, 0.f);
      *(f16x4*)(outb + (size_t)bx * 32768 + (size_t)o * 128 + hwb) = w;
    }
  }
}

// ---------------- Merged Theta2 + Ta ----------------
__global__ __launch_bounds__(256) void kTT(const float* __restrict__ vect, const float* __restrict__ thwT,
                                           float* __restrict__ P,
                                           const float* __restrict__ embed, const float* __restrict__ tteT,
                                           const float* __restrict__ tte_b, const float* __restrict__ te_w,
                                           float* __restrict__ Sta) {
  __shared__ float V[512];
  __shared__ __align__(16) float E[256 * 64];
  __shared__ float Red[16 * 64];
  int bid = blockIdx.x;
  int t = threadIdx.x;
  if (bid < 512) {
    int bt = bid & 127, kq = bid >> 7;
    const float* src = vect + (size_t)bt * 2048 + kq * 512;
    if (t < 128) *(float4*)(V + t * 4) = *(const float4*)(src + t * 4);
    __syncthreads();
    const float* wp = thwT + (size_t)kq * 512 * 256 + t;
    float acc = 0.f;
#pragma unroll 8
    for (int c = 0; c < 512; ++c)
      acc = fmaf(wp[(size_t)c * 256], V[c], acc);
    P[((size_t)kq * 128 + bt) * 256 + t] = acc;
    return;
  }
  int i = bid - 512;
  int n = i & 63, gate = (i >> 6) & 1, hh = (i >> 7) & 1;
  int b = n >> 2, p = n & 3;
  const float* eA = embed + (size_t)(b * 8 + 2 * p + gate) * 16384 + hh * 64;
  const float* eB = embed + (size_t)(b * 8 + 2 * p + 1 - gate) * 16384 + hh * 64;
  for (int r = 0; r < 8; ++r) {
    int f = r * 256 + t;
    int ch = f >> 4, q = (f & 15) * 4;
    *(float4*)(E + ch * 64 + q) = *(const float4*)(eA + (size_t)ch * 128 + q);
  }
  for (int r = 0; r < 8; ++r) {
    int f = r * 256 + t;
    int ch = f >> 4, q = (f & 15) * 4;
    *(float4*)(E + (128 + ch) * 64 + q) = *(const float4*)(eB + (size_t)ch * 128 + q);
  }
  __syncthreads();
  int ty = t >> 4, tx = t & 15;
  float acc[8][4] = {};
  for (int c = 0; c < 256; ++c) {
    float w8[8];
    *(float4*)w8 = *(const float4*)(tteT + (size_t)c * 128 + ty * 8);
    *(float4*)(w8 + 4) = *(const float4*)(tteT + (size_t)c * 128 + ty * 8 + 4);
    float4 g = *(const float4*)(E + c * 64 + tx * 4);
    for (int ii = 0; ii < 8; ++ii) {
      acc[ii][0] = fmaf(w8[ii], g.x, acc[ii][0]);
      acc[ii][1] = fmaf(w8[ii], g.y, acc[ii][1]);
      acc[ii][2] = fmaf(w8[ii], g.z, acc[ii][2]);
      acc[ii][3] = fmaf(w8[ii], g.w, acc[ii][3]);
    }
  }
  float par[4] = {0.f, 0.f, 0.f, 0.f};
  for (int ii = 0; ii < 8; ++ii) {
    int o = ty * 8 + ii;
    float tb = tte_b[o], tw = te_w[o];
    for (int j = 0; j < 4; ++j)
      par[j] += tw * fmaxf(acc[ii][j] + tb, 0.f);
  }
  for (int j = 0; j < 4; ++j) Red[ty * 64 + tx * 4 + j] = par[j];
  __syncthreads();
  if (t < 64) {
    float s = 0.f;
    for (int g = 0; g < 16; ++g) s += Red[g * 64 + t];
    Sta[(size_t)gate * 8192 + n * 128 + hh * 64 + t] = s;
  }
}

// ---------------- Merged MlpA + Gs (gammaF/betaF are f16) ----------------
__global__ __launch_bounds__(256) void kAG(const float* __restrict__ P, const float* __restrict__ thb,
                                           const float* __restrict__ w1T, const float* __restrict__ b1,
                                           float* __restrict__ h1,
                                           const f16* __restrict__ gammaFh, const f16* __restrict__ betaFh,
                                           float* __restrict__ Gs0, float* __restrict__ Gs1) {
  __shared__ float x0[256], x1[256];
  __shared__ float ra[256], rb[256];
  __shared__ __align__(16) float As[16 * 128];
  __shared__ __align__(16) float Bs[16 * 64];
  int bid = blockIdx.x;
  int t = threadIdx.x;
  if (bid < 256) {
    int bp = bid & 63, och = bid >> 6;
    int b = bp >> 2, p = bp & 3;
    int bt0 = b * 8 + 2 * p, bt1 = bt0 + 1;
    {
      float a0 = 0.f, a1 = 0.f;
      for (int q = 0; q < 4; ++q) {
        a0 += P[((size_t)q * 128 + bt0) * 256 + t];
        a1 += P[((size_t)q * 128 + bt1) * 256 + t];
      }
      float tb = thb[t];
      x0[t] = fmaxf(a0 + tb, 0.f);
      x1[t] = fmaxf(a1 + tb, 0.f);
    }
    __syncthreads();
    int o = och * 64 + (t & 63);
    int ks = t >> 6;
    const float* xa = (ks < 2) ? x0 : x1;
    const float* xb = (ks < 2) ? x1 : x0;
    int kbase = ks * 128;
    int xoff = (ks < 2) ? kbase : kbase - 256;
    float aa = 0.f, ab = 0.f;
#pragma unroll 8
    for (int ii = 0; ii < 128; ++ii) {
      float w = w1T[(size_t)(kbase + ii) * 256 + o];
      aa = fmaf(w, xa[xoff + ii], aa);
      ab = fmaf(w, xb[xoff + ii], ab);
    }
    ra[t] = aa;
    rb[t] = ab;
    __syncthreads();
    if (t < 64) {
      float sa = ra[t] + ra[64 + t] + ra[128 + t] + ra[192 + t];
      float sb = rb[t] + rb[64 + t] + rb[128 + t] + rb[192 + t];
      float bb = b1[o];
      h1[((size_t)bp * 2) * 256 + o] = fmaxf(sa + bb, 0.f);
      h1[((size_t)bp * 2 + 1) * 256 + o] = fmaxf(sb + bb, 0.f);
    }
    return;
  }
  int i = bid - 256;
  int n = i & 63, which = (i >> 6) & 1, th = (i >> 7) & 1;
  int b = n >> 2, p = n & 3;
  int tg = 2 * p + which;
  int tb = 2 * p + 1 - which;
  const f16* A = gammaFh + (size_t)(b * 8 + tg) * 32768;
  const f16* Bm = betaFh + (size_t)(b * 8 + tb) * 32768;
  float* out = (which ? Gs1 : Gs0) + (size_t)n * 16384;
  int ty = t >> 4, tx = t & 15;
  float acc[8][4] = {};
  for (int c0 = 0; c0 < 256; c0 += 16) {
    {
      int cc = t >> 4, col8 = (t & 15) * 8;
      f16x8 v = *(const f16x8*)(A + (size_t)(c0 + cc) * 128 + col8);
      for (int j = 0; j < 8; ++j) As[cc * 128 + col8 + j] = (float)v[j];
    }
    if (t < 128) {
      int cc = t >> 3, col8 = (t & 7) * 8;
      f16x8 v = *(const f16x8*)(Bm + (size_t)(c0 + cc) * 128 + th * 64 + col8);
      for (int j = 0; j < 8; ++j) Bs[cc * 64 + col8 + j] = (float)v[j];
    }
    __syncthreads();
    for (int cc = 0; cc < 16; ++cc) {
      float a8[8];
      *(float4*)a8 = *(const float4*)(As + cc * 128 + ty * 8);
      *(float4*)(a8 + 4) = *(const float4*)(As + cc * 128 + ty * 8 + 4);
      float4 b4 = *(const float4*)(Bs + cc * 64 + tx * 4);
      for (int ii = 0; ii < 8; ++ii) {
        acc[ii][0] = fmaf(a8[ii], b4.x, acc[ii][0]);
        acc[ii][1] = fmaf(a8[ii], b4.y, acc[ii][1]);
        acc[ii][2] = fmaf(a8[ii], b4.z, acc[ii][2]);
        acc[ii][3] = fmaf(a8[ii], b4.w, acc[ii][3]);
      }
    }
    __syncthreads();
  }
  for (int ii = 0; ii < 8; ++ii) {
    *(float4*)(out + (size_t)(ty * 8 + ii) * 128 + th * 64 + tx * 4) =
        make_float4(acc[ii][0], acc[ii][1], acc[ii][2], acc[ii][3]);
  }
}

// ---------------- Merged MlpB + Gj ----------------
__global__ __launch_bounds__(256) void kBG(const float* __restrict__ h1, const float* __restrict__ w2T,
                                           const float* __restrict__ b2,
                                           float* __restrict__ p00, float* __restrict__ p01,
                                           const float* __restrict__ Gs0, const float* __restrict__ Gs1,
                                           const float* __restrict__ ggT, const float* __restrict__ gg_b,
                                           const float* __restrict__ te_w, float* __restrict__ Sgj) {
  __shared__ float ha[256], hb[256];
  __shared__ float G0h[64 * 129];
  __shared__ __align__(16) float G1c[128 * 64];
  __shared__ float Red[16 * 64];
  int bid = blockIdx.x;
  int t = threadIdx.x;
  if (bid < 512) {
    int bp = bid & 63, chc = bid >> 6;
    ha[t] = h1[((size_t)bp * 2) * 256 + t];
    hb[t] = h1[((size_t)bp * 2 + 1) * 256 + t];
    __syncthreads();
    int ch = chc * 256 + t;
    float sa = 0.f, sb = 0.f;
#pragma unroll 8
    for (int k = 0; k < 256; ++k) {
      float w = w2T[(size_t)k * 2048 + ch];
      sa = fmaf(w, ha[k], sa);
      sb = fmaf(w, hb[k], sb);
    }
    p00[(size_t)bp * 2048 + ch] = sigmoidf_(sa + b2[ch]);
    p01[(size_t)bp * 2048 + ch] = sigmoidf_(sb + b2[ch]);
    return;
  }
  int i = bid - 512;
  int n = i & 63, gate = (i >> 6) & 1, hh = (i >> 7) & 1;
  const float* srcT = (gate == 0 ? Gs0 : Gs1) + (size_t)n * 16384;
  const float* srcC = (gate == 0 ? Gs1 : Gs0) + (size_t)n * 16384;
  for (int r = 0; r < 8; ++r) {
    int f = r * 256 + t;
    int hwl = f >> 5, c4 = (f & 31) * 4;
    float4 v = *(const float4*)(srcT + (size_t)(hh * 64 + hwl) * 128 + c4);
    G0h[hwl * 129 + c4 + 0] = v.x;
    G0h[hwl * 129 + c4 + 1] = v.y;
    G0h[hwl * 129 + c4 + 2] = v.z;
    G0h[hwl * 129 + c4 + 3] = v.w;
  }
  for (int r = 0; r < 8; ++r) {
    int f = r * 256 + t;
    int c = f >> 4, q = (f & 15) * 4;
    *(float4*)(G1c + c * 64 + q) = *(const float4*)(srcC + (size_t)c * 128 + hh * 64 + q);
  }
  __syncthreads();
  int ty = t >> 4, tx = t & 15;
  float acc[8][4] = {};
  for (int c = 0; c < 128; ++c) {
    float w8[8];
    *(float4*)w8 = *(const float4*)(ggT + (size_t)c * 128 + ty * 8);
    *(float4*)(w8 + 4) = *(const float4*)(ggT + (size_t)c * 128 + ty * 8 + 4);
    float g4[4];
    for (int j = 0; j < 4; ++j) g4[j] = G0h[(tx * 4 + j) * 129 + c];
    for (int ii = 0; ii < 8; ++ii)
      for (int j = 0; j < 4; ++j)
        acc[ii][j] = fmaf(w8[ii], g4[j], acc[ii][j]);
  }
  for (int c = 0; c < 128; ++c) {
    float w8[8];
    *(float4*)w8 = *(const float4*)(ggT + (size_t)(128 + c) * 128 + ty * 8);
    *(float4*)(w8 + 4) = *(const float4*)(ggT + (size_t)(128 + c) * 128 + ty * 8 + 4);
    float4 g = *(const float4*)(G1c + c * 64 + tx * 4);
    for (int ii = 0; ii < 8; ++ii) {
      acc[ii][0] = fmaf(w8[ii], g.x, acc[ii][0]);
      acc[ii][1] = fmaf(w8[ii], g.y, acc[ii][1]);
      acc[ii][2] = fmaf(w8[ii], g.z, acc[ii][2]);
      acc[ii][3] = fmaf(w8[ii], g.w, acc[ii][3]);
    }
  }
  float par[4] = {0.f, 0.f, 0.f, 0.f};
  for (int ii = 0; ii < 8; ++ii) {
    int o = ty * 8 + ii;
    float gb = gg_b[o], tw = te_w[128 + o];
    for (int j = 0; j < 4; ++j)
      par[j] += tw * fmaxf(acc[ii][j] + gb, 0.f);
  }
  for (int j = 0; j < 4; ++j) Red[ty * 64 + tx * 4 + j] = par[j];
  __syncthreads();
  if (t < 64) {
    float s = 0.f;
    for (int g = 0; g < 16; ++g) s += Red[g * 64 + t];
    Sgj[(size_t)gate * 8192 + n * 128 + hh * 64 + t] = s;
  }
}

// ---------------- final elementwise (gate sigmoid fused): out = relu(p00*pa*f0 + p01*pb*f1)^2 ----
__global__ __launch_bounds__(256) void kFinal(const float* __restrict__ featmap, const float* __restrict__ p00,
                                              const float* __restrict__ p01, const float* __restrict__ Sta,
                                              const float* __restrict__ Sgj, const float* __restrict__ te_s,
                                              const float* __restrict__ te_b, float* __restrict__ out) {
  int fid = blockIdx.x * 256 + threadIdx.x;
  int h4 = (fid & 31) * 4;
  int c = (fid >> 5) & 2047;
  int bp = fid >> 16;
  int b = bp >> 2, p = bp & 3;
  float ga = p00[(size_t)bp * 2048 + c];
  float gb = p01[(size_t)bp * 2048 + c];
  float ts = te_s[0], tbv = te_b[0];
  float4 sa0 = *(const float4*)(Sta + (size_t)bp * 128 + h4);
  float4 sg0 = *(const float4*)(Sgj + (size_t)bp * 128 + h4);
  float4 sa1 = *(const float4*)(Sta + 8192 + (size_t)bp * 128 + h4);
  float4 sg1 = *(const float4*)(Sgj + 8192 + (size_t)bp * 128 + h4);
  float4 pa4, pb4;
  pa4.x = sigmoidf_(ts * (sa0.x + sg0.x) + tbv);
  pa4.y = sigmoidf_(ts * (sa0.y + sg0.y) + tbv);
  pa4.z = sigmoidf_(ts * (sa0.z + sg0.z) + tbv);
  pa4.w = sigmoidf_(ts * (sa0.w + sg0.w) + tbv);
  pb4.x = sigmoidf_(ts * (sa1.x + sg1.x) + tbv);
  pb4.y = sigmoidf_(ts * (sa1.y + sg1.y) + tbv);
  pb4.z = sigmoidf_(ts * (sa1.z + sg1.z) + tbv);
  pb4.w = sigmoidf_(ts * (sa1.w + sg1.w) + tbv);
  const float* f0 = featmap + (size_t)(b * 8 + 2 * p) * 262144 + (size_t)c * 128 + h4;
  const float* f1 = f0 + 262144;
  float4 v0 = *(const float4*)f0;
  float4 v1 = *(const float4*)f1;
  float4 o4;
  float r;
  r = fmaxf(ga * pa4.x * v0.x + gb * pb4.x * v1.x, 0.f); o4.x = r * r;
  r = fmaxf(ga * pa4.y * v0.y + gb * pb4.y * v1.y, 0.f); o4.y = r * r;
  r = fmaxf(ga * pa4.z * v0.z + gb * pb4.z * v1.z, 0.f); o4.z = r * r;
  r = fmaxf(ga * pa4.w * v0.w + gb * pb4.w * v1.w, 0.f); o4.w = r * r;
  *(float4*)(out + (size_t)fid * 4) = o4;
}

extern "C" void kernel_launch(void* const* d_in, const int* in_sizes, int n_in,
                              void* d_out, int out_size, void* d_ws, size_t ws_size,
                              hipStream_t stream) {
  (void)in_sizes; (void)n_in; (void)out_size; (void)ws_size;
  const float* featmap    = (const float*)d_in[0];
  const float* re_featmap = (const float*)d_in[1];
  const float* vect       = (const float*)d_in[2];
  const float* embed      = (const float*)d_in[3];
  const float* gamma_w    = (const float*)d_in[4];
  const float* gamma_s    = (const float*)d_in[5];
  const float* gamma_b    = (const float*)d_in[6];
  const float* beta_w     = (const float*)d_in[7];
  const float* beta_s     = (const float*)d_in[8];
  const float* beta_b     = (const float*)d_in[9];
  const float* gg_w       = (const float*)d_in[10];
  const float* gg_s       = (const float*)d_in[11];
  const float* gg_b       = (const float*)d_in[12];
  const float* tte_w      = (const float*)d_in[13];
  const float* tte_s      = (const float*)d_in[14];
  const float* tte_b      = (const float*)d_in[15];
  const float* te_w       = (const float*)d_in[16];
  const float* te_s       = (const float*)d_in[17];
  const float* te_b       = (const float*)d_in[18];
  const float* theta_w    = (const float*)d_in[19];
  const float* theta_b    = (const float*)d_in[20];
  const float* cp_w1      = (const float*)d_in[21];
  const float* cp_b1      = (const float*)d_in[22];
  const float* cp_w2      = (const float*)d_in[23];
  const float* cp_b2      = (const float*)d_in[24];
  float* out = (float*)d_out;

  char* w = (char*)d_ws;
  f16* Wf  = (f16*)w;   w += (size_t)512 * 2048 * 2;
  f16* gammaFh = (f16*)w; w += (size_t)128 * 256 * 128 * 2;
  f16* betaFh  = (f16*)w; w += (size_t)128 * 256 * 128 * 2;
  float* Gs0    = (float*)w; w += (size_t)64 * 128 * 128 * 4;
  float* Gs1    = (float*)w; w += (size_t)64 * 128 * 128 * 4;
  float* ggT    = (float*)w; w += (size_t)256 * 128 * 4;
  float* tteT   = (float*)w; w += (size_t)256 * 128 * 4;
  float* thwT   = (float*)w; w += (size_t)2048 * 256 * 4;
  float* w1T    = (float*)w; w += (size_t)512 * 256 * 4;
  float* w2T    = (float*)w; w += (size_t)256 * 2048 * 4;
  float* P      = (float*)w; w += (size_t)4 * 128 * 256 * 4;
  float* h1     = (float*)w; w += (size_t)64 * 2 * 256 * 4;
  float* Sta    = (float*)w; w += (size_t)2 * 64 * 128 * 4;
  float* Sgj    = (float*)w; w += (size_t)2 * 64 * 128 * 4;
  float* p00    = (float*)w; w += (size_t)64 * 2048 * 4;
  float* p01    = (float*)w; w += (size_t)64 * 2048 * 4;

  kPP<<<816, 256, 0, stream>>>(gamma_w, gamma_s, beta_w, beta_s, gg_w, gg_s, tte_w, tte_s,
                               theta_w, cp_w1, cp_w2, Wf, ggT, tteT, thwT, w1T, w2T);
  kGemm8<<<256, 512, 0, stream>>>(re_featmap, Wf, gamma_b, beta_b, gammaFh, betaFh);
  kTT<<<768, 256, 0, stream>>>(vect, thwT, P, embed, tteT, tte_b, te_w, Sta);
  kAG<<<512, 256, 0, stream>>>(P, theta_b, w1T, cp_b1, h1, gammaFh, betaFh, Gs0, Gs1);
  kBG<<<768, 256, 0, stream>>>(h1, w2T, cp_b2, p00, p01, Gs0, Gs1, ggT, gg_b, te_w, Sgj);
  kFinal<<<16384, 256, 0, stream>>>(featmap, p00, p01, Sta, Sgj, te_s, te_b, out);
}